// Round 5
// baseline (579.706 us; speedup 1.0000x reference)
//
#include <hip/hip_runtime.h>
#include <hip/hip_fp16.h>

static constexpr int N0 = 50000;
static constexpr int N1 = 200000;
static constexpr int N2 = 100000;
static constexpr int NNZ0 = 600000;
static constexpr int NNZ1 = 1000000;
static constexpr int NNZ2 = 600000;
static constexpr int FIN = 500;

// concatenated count layout: [L0 | L1a | L1b | L2 | B1 | B2]
static constexpr int SEG_L0 = 0;
static constexpr int SEG_L1A = 50000;
static constexpr int SEG_L1B = 250000;
static constexpr int SEG_L2 = 450000;
static constexpr int SEG_B1 = 550000;
static constexpr int SEG_B2 = 600000;
static constexpr int CNT_TOT = 800000;
static constexpr int TOT_E = NNZ0 + NNZ1 + NNZ1 + NNZ2 + 2 * N1 + 3 * N2;  // 3.9M
// radix partition: 512 partition blocks x 1563 coarse buckets (512 rows each).
static constexpr int NBLK = 512;
static constexpr int EPB = (TOT_E + NBLK - 1) / NBLK;        // 7618 entries/block
static constexpr int CB_SHIFT = 9;                           // 512 rows per coarse bucket
static constexpr int CB = (CNT_TOT + (1 << CB_SHIFT) - 1) >> CB_SHIFT;  // 1563
static constexpr int BH_N = CB * NBLK;                       // 800256
static constexpr int SCAN_CHUNK = 4096;
static constexpr int BH_SCAN_BLOCKS = (BH_N + SCAN_CHUNK - 1) / SCAN_CHUNK;  // 196 (<=256 cap)

typedef __attribute__((ext_vector_type(8))) short bf16x8;
typedef __attribute__((ext_vector_type(8))) _Float16 f16x8;
typedef __attribute__((ext_vector_type(4))) float f32x4;

typedef const unsigned int __attribute__((address_space(1)))* gas_u32p;
typedef unsigned int __attribute__((address_space(3)))* las_u32p;

__device__ __forceinline__ unsigned short f2bf(float f) {
  unsigned int b = __float_as_uint(f);
  b = (b + 0x7FFFu + ((b >> 16) & 1u)) >> 16;   // RNE
  return (unsigned short)b;
}

// ---------- pack X0 -> binary bitmasks: 512 bits = 16 uints per row (3.2 MB, L2-resident) ----------
__global__ __launch_bounds__(256) void pack_bits_kernel(const float* __restrict__ X0,
                                                        unsigned int* __restrict__ Xbit) {
  int row = blockIdx.x * 4 + (threadIdx.x >> 6);
  if (row >= N0) return;
  int lane = threadIdx.x & 63;
  const float* xr = X0 + (long long)row * FIN;
#pragma unroll
  for (int i = 0; i < 8; ++i) {
    int c = i * 64 + lane;
    bool pred = (c < FIN) && (xr[c] != 0.0f);
    unsigned long long m = __ballot(pred);
    if (lane == 0) {
      Xbit[row * 16 + 2 * i] = (unsigned int)m;
      Xbit[row * 16 + 2 * i + 1] = (unsigned int)(m >> 32);
    }
  }
}

// ---------- pack W -> bf16 MFMA B-fragment layout: [level][kc][nb][lane][j] ----------
__global__ void pack_w_kernel(const float* __restrict__ W, unsigned short* __restrict__ Bp) {
  int g = blockIdx.x * 256 + threadIdx.x;
  if (g >= 3 * 65536) return;
  int j = g & 7;
  int lane = (g >> 3) & 63;
  int nb = (g >> 9) & 7;
  int kc = (g >> 12) & 15;
  int level = g >> 16;
  int k = kc * 32 + (lane >> 4) * 8 + j;
  int col128 = nb * 16 + (lane & 15);
  int head = level * 2 + (col128 >> 6);
  int col = col128 & 63;
  float f = 0.0f;
  if (k < FIN) f = W[((long long)head * FIN + k) * 64 + col];
  Bp[g] = f2bf(f);
}

// ---------- pack triW -> f16 B-fragment layout: [kc(2)][nb(4)][lane][j] ----------
__global__ void pack_wt_kernel(const float* __restrict__ triW, __half* __restrict__ Wt) {
  int g = blockIdx.x * 256 + threadIdx.x;
  if (g >= 4096) return;
  int j = g & 7;
  int lane = (g >> 3) & 63;
  int nb = (g >> 9) & 3;
  int kc = g >> 11;
  int k = kc * 32 + (lane >> 4) * 8 + j;
  int col = nb * 16 + (lane & 15);
  Wt[g] = __float2half(triW[k * 64 + col]);
}

// ---------- fused bit-gather(AND) + in-register bf16 expansion + MFMA ----------
// B-fragments staged into LDS via global_load_lds (zero VGPR cost), double-buffered,
// one raw barrier per kc (R3: fixed register-starvation VMEM serialization).
template <int NSRC>
__global__ __launch_bounds__(256, 4) void gemm_sat_kernel(
    const unsigned int* __restrict__ Xbit, const int* __restrict__ srcidx,
    const unsigned short* __restrict__ Bp, const float* __restrict__ bvec,
    const float* __restrict__ a2w, const float* __restrict__ a2b, int head_lo,
    int M, __half* __restrict__ h_lo, __half* __restrict__ h_hi,
    float* __restrict__ e_lo, float* __restrict__ e_hi) {
  __shared__ __align__(16) unsigned int Sb[128 * 20];
  __shared__ __align__(16) unsigned short Bs[2][4096];   // 2 x 8KB double buffer
  const int tid = threadIdx.x;
  const int m0 = blockIdx.x * 128;
  const int wave = tid >> 6;
  const int lane = tid & 63;
  {
    // 2 threads per row: thread handles uint4 chunks {2*hf, 2*hf+1} of the 64B row mask
    int rg = m0 + (tid >> 1);
    int hf = tid & 1;
    uint4 a[2];
#pragma unroll
    for (int c2 = 0; c2 < 2; ++c2) a[c2] = make_uint4(0u, 0u, 0u, 0u);
    if (rg < M) {
      if (NSRC == 1) {
        const uint4* up = (const uint4*)(Xbit + (long long)rg * 16);
#pragma unroll
        for (int c2 = 0; c2 < 2; ++c2) a[c2] = up[hf * 2 + c2];
      } else if (NSRC == 2) {
        const uint4* up = (const uint4*)(Xbit + (long long)srcidx[2 * rg + 0] * 16);
        const uint4* vp = (const uint4*)(Xbit + (long long)srcidx[2 * rg + 1] * 16);
#pragma unroll
        for (int c2 = 0; c2 < 2; ++c2) {
          uint4 u = up[hf * 2 + c2], v = vp[hf * 2 + c2];
          a[c2] = make_uint4(u.x & v.x, u.y & v.y, u.z & v.z, u.w & v.w);
        }
      } else {
        const uint4* up = (const uint4*)(Xbit + (long long)srcidx[3 * rg + 0] * 16);
        const uint4* vp = (const uint4*)(Xbit + (long long)srcidx[3 * rg + 1] * 16);
        const uint4* wp = (const uint4*)(Xbit + (long long)srcidx[3 * rg + 2] * 16);
#pragma unroll
        for (int c2 = 0; c2 < 2; ++c2) {
          uint4 u = up[hf * 2 + c2], v = vp[hf * 2 + c2], w = wp[hf * 2 + c2];
          a[c2] = make_uint4(u.x & v.x & w.x, u.y & v.y & w.y, u.z & v.z & w.z, u.w & v.w & w.w);
        }
      }
    }
#pragma unroll
    for (int c2 = 0; c2 < 2; ++c2)
      *(uint4*)(Sb + (tid >> 1) * 20 + (hf * 2 + c2) * 4) = a[c2];
  }

  // stage B slab for kc (8KB = 4 waves x 2 instrs x 1KB) direct to LDS, no VGPR round-trip.
  auto stageB = [&](int buf, int kc2) {
    int chunk0 = wave * 2;
    const unsigned short* g0 = Bp + kc2 * 4096 + chunk0 * 512 + lane * 8;
    __builtin_amdgcn_global_load_lds((gas_u32p)(const void*)g0,
                                     (las_u32p)(void*)&Bs[buf][chunk0 * 512], 16, 0, 0);
    __builtin_amdgcn_global_load_lds((gas_u32p)(const void*)(g0 + 512),
                                     (las_u32p)(void*)&Bs[buf][chunk0 * 512 + 512], 16, 0, 0);
  };
  stageB(0, 0);
  __syncthreads();   // full drain once: Sb writes + Bs[0] stage complete

  const int quad = lane >> 4;
  const int l16 = lane & 15;
  f32x4 acc[8][2];   // [nb][sub]
#pragma unroll
  for (int i = 0; i < 8; ++i)
#pragma unroll
    for (int s = 0; s < 2; ++s) acc[i][s] = (f32x4){0.f, 0.f, 0.f, 0.f};

  for (int kc = 0; kc < 16; ++kc) {
    const int cur = kc & 1;
    if (kc < 15) stageB(cur ^ 1, kc + 1);   // issue next stage first (overlaps compute)
    bf16x8 af[2];
#pragma unroll
    for (int sub = 0; sub < 2; ++sub) {
      unsigned int bw = Sb[(wave * 32 + sub * 16 + l16) * 20 + kc];
      unsigned int byte = (bw >> (quad * 8)) & 0xFFu;
#pragma unroll
      for (int j = 0; j < 4; ++j) {
        unsigned int b2 = (byte >> (2 * j)) & 3u;
        ((unsigned int*)&af[sub])[j] = ((b2 & 1u) | ((b2 & 2u) << 15)) * 0x3F80u;
      }
    }
#pragma unroll
    for (int nb = 0; nb < 8; ++nb) {
      bf16x8 bf = *(const bf16x8*)&Bs[cur][(nb * 64 + lane) * 8];
#pragma unroll
      for (int sub = 0; sub < 2; ++sub)
        acc[nb][sub] = __builtin_amdgcn_mfma_f32_16x16x32_bf16(af[sub], bf, acc[nb][sub], 0, 0, 0);
    }
    if (kc < 15) {
      asm volatile("s_waitcnt vmcnt(0)" ::: "memory");   // next stage landed
      __builtin_amdgcn_sched_barrier(0);
      __builtin_amdgcn_s_barrier();                       // raw barrier: no lgkm/vm drain churn
    }
  }

  float bia[8], aw[8];
#pragma unroll
  for (int nb = 0; nb < 8; ++nb) {
    int col128 = nb * 16 + l16;
    int hh = col128 >> 6, col = col128 & 63;
    bia[nb] = bvec[(head_lo + hh) * 64 + col];
    aw[nb] = a2w[(head_lo + hh) * 64 + col];
  }
  float blo = a2b[head_lo], bhi = a2b[head_lo + 1];
#pragma unroll
  for (int sub = 0; sub < 2; ++sub) {
    float plo[4] = {0.f, 0.f, 0.f, 0.f};
    float phi[4] = {0.f, 0.f, 0.f, 0.f};
#pragma unroll
    for (int nb = 0; nb < 8; ++nb) {
      int col128 = nb * 16 + l16;
      int hh = col128 >> 6, col = col128 & 63;
      __half* hdst = hh ? h_hi : h_lo;
#pragma unroll
      for (int reg = 0; reg < 4; ++reg) {
        int rg = m0 + wave * 32 + sub * 16 + quad * 4 + reg;   // C/D: row=quad*4+reg, col=l16
        float v = acc[nb][sub][reg] + bia[nb];
        if (rg < M) hdst[(long long)rg * 64 + col] = __float2half(v);
        if (hh) phi[reg] += v * aw[nb]; else plo[reg] += v * aw[nb];
      }
    }
#pragma unroll
    for (int off = 1; off < 16; off <<= 1) {
#pragma unroll
      for (int reg = 0; reg < 4; ++reg) {
        plo[reg] += __shfl_xor(plo[reg], off);
        phi[reg] += __shfl_xor(phi[reg], off);
      }
    }
    if (l16 == 0) {
#pragma unroll
      for (int reg = 0; reg < 4; ++reg) {
        int rg = m0 + wave * 32 + sub * 16 + quad * 4 + reg;
        if (rg < M) {
          e_lo[rg] = __expf(plo[reg] + blo);   // |s2| small by construction: no max needed
          e_hi[rg] = __expf(phi[reg] + bhi);
        }
      }
    }
  }
}

// ---------- entry decode shared by partition passes ----------
template <bool NEED_VAL>
__device__ __forceinline__ void decode_entry(
    int g, const int* __restrict__ r0, const int* __restrict__ r1a,
    const int* __restrict__ r1b, const int* __restrict__ r2,
    const int* __restrict__ rb1, const int* __restrict__ rb2, int& row, int& val) {
  if (g < 600000) { int l = g; row = SEG_L0 + r0[l]; if (NEED_VAL) val = r0[NNZ0 + l]; }
  else if (g < 1600000) { int l = g - 600000; row = SEG_L1A + r1a[l]; if (NEED_VAL) val = r1a[NNZ1 + l]; }
  else if (g < 2600000) { int l = g - 1600000; row = SEG_L1B + r1b[l]; if (NEED_VAL) val = r1b[NNZ1 + l]; }
  else if (g < 3200000) { int l = g - 2600000; row = SEG_L2 + r2[l]; if (NEED_VAL) val = r2[NNZ2 + l]; }
  else if (g < 3600000) { int l = g - 3200000; row = SEG_B1 + rb1[l]; val = l; }   // B1: entry id
  else { int l = g - 3600000; row = SEG_B2 + rb2[l]; val = l; }                    // B2: entry id
}

// ---------- pass 1: per-(block, coarse-bucket) histogram via LDS, 4x-unrolled MLP ----------
__global__ __launch_bounds__(256) void blkhist_kernel(
    const int* __restrict__ r0, const int* __restrict__ r1a, const int* __restrict__ r1b,
    const int* __restrict__ r2, const int* __restrict__ rb1, const int* __restrict__ rb2,
    int* __restrict__ bh) {
  __shared__ int hcnt[CB];
  int blk = blockIdx.x;
  for (int i = threadIdx.x; i < CB; i += 256) hcnt[i] = 0;
  __syncthreads();
  int g0 = blk * EPB;
  int g1 = g0 + EPB; if (g1 > TOT_E) g1 = TOT_E;
  int g = g0 + threadIdx.x;
  for (; g + 768 < g1; g += 1024) {
    int ra, rb, rc, rd, v;
    decode_entry<false>(g, r0, r1a, r1b, r2, rb1, rb2, ra, v);
    decode_entry<false>(g + 256, r0, r1a, r1b, r2, rb1, rb2, rb, v);
    decode_entry<false>(g + 512, r0, r1a, r1b, r2, rb1, rb2, rc, v);
    decode_entry<false>(g + 768, r0, r1a, r1b, r2, rb1, rb2, rd, v);
    atomicAdd(&hcnt[ra >> CB_SHIFT], 1);
    atomicAdd(&hcnt[rb >> CB_SHIFT], 1);
    atomicAdd(&hcnt[rc >> CB_SHIFT], 1);
    atomicAdd(&hcnt[rd >> CB_SHIFT], 1);
  }
  for (; g < g1; g += 256) {
    int row, val;
    decode_entry<false>(g, r0, r1a, r1b, r2, rb1, rb2, row, val);
    atomicAdd(&hcnt[row >> CB_SHIFT], 1);
  }
  __syncthreads();
  for (int i = threadIdx.x; i < CB; i += 256) bh[i * NBLK + blk] = hcnt[i];
}

// ---------- 3-phase scan (parameterized size) ----------
__global__ __launch_bounds__(256) void scan_partial_kernel(const int* __restrict__ cnt,
                                                           int* __restrict__ bsum, int n) {
  __shared__ int s[256];
  int b = blockIdx.x, t = threadIdx.x;
  int base = b * SCAN_CHUNK + t * 16;
  int sum = 0;
#pragma unroll
  for (int i = 0; i < 16; ++i) {
    int idx = base + i;
    if (idx < n) sum += cnt[idx];
  }
  s[t] = sum;
  __syncthreads();
  for (int off = 128; off > 0; off >>= 1) {
    if (t < off) s[t] += s[t + off];
    __syncthreads();
  }
  if (t == 0) bsum[b] = s[0];
}

__global__ __launch_bounds__(256) void scan_bsum_kernel(int* __restrict__ bsum, int nb) {
  __shared__ int s[256];
  int t = threadIdx.x;
  int v = (t < nb) ? bsum[t] : 0;
  s[t] = v;
  __syncthreads();
  for (int off = 1; off < 256; off <<= 1) {
    int u = (t >= off) ? s[t - off] : 0;
    __syncthreads();
    s[t] += u;
    __syncthreads();
  }
  if (t < nb) bsum[t] = (t == 0) ? 0 : s[t - 1];
  if (t == 0) bsum[nb] = s[nb - 1];
}

__global__ __launch_bounds__(256) void scan_write_kernel(const int* __restrict__ cnt,
                                                         const int* __restrict__ bsum,
                                                         int* __restrict__ gout, int n, int nb) {
  __shared__ int s[256];
  int b = blockIdx.x, t = threadIdx.x;
  int base = b * SCAN_CHUNK + t * 16;
  int loc[16];
  int sum = 0;
#pragma unroll
  for (int i = 0; i < 16; ++i) {
    int idx = base + i;
    int v = (idx < n) ? cnt[idx] : 0;
    loc[i] = sum;
    sum += v;
  }
  s[t] = sum;
  __syncthreads();
  for (int off = 1; off < 256; off <<= 1) {
    int u = (t >= off) ? s[t - off] : 0;
    __syncthreads();
    s[t] += u;
    __syncthreads();
  }
  int toff = bsum[b] + ((t == 0) ? 0 : s[t - 1]);
#pragma unroll
  for (int i = 0; i < 16; ++i) {
    int idx = base + i;
    if (idx < n) gout[idx] = toff + loc[i];
  }
  if (b == 0 && t == 0) gout[n] = bsum[nb];
}

// ---------- pass 2: write packed (row_lo,val) into block-PRIVATE per-bucket runs, 4x MLP ----------
// R5: stage entry packed to 4B -- within a bucket only row&511 (9b) + val (<=19b) needed.
__global__ __launch_bounds__(256) void stage_part_kernel(
    const int* __restrict__ r0, const int* __restrict__ r1a, const int* __restrict__ r1b,
    const int* __restrict__ r2, const int* __restrict__ rb1, const int* __restrict__ rb2,
    const int* __restrict__ bhoff, int* __restrict__ stage) {
  __shared__ int lcur[CB];
  int blk = blockIdx.x;
  for (int i = threadIdx.x; i < CB; i += 256) lcur[i] = bhoff[i * NBLK + blk];
  __syncthreads();
  int g0 = blk * EPB;
  int g1 = g0 + EPB; if (g1 > TOT_E) g1 = TOT_E;
  const int rmask = (1 << CB_SHIFT) - 1;
  int g = g0 + threadIdx.x;
  for (; g + 768 < g1; g += 1024) {
    int ra, rb, rc, rd, va, vb, vc, vd;
    decode_entry<true>(g, r0, r1a, r1b, r2, rb1, rb2, ra, va);
    decode_entry<true>(g + 256, r0, r1a, r1b, r2, rb1, rb2, rb, vb);
    decode_entry<true>(g + 512, r0, r1a, r1b, r2, rb1, rb2, rc, vc);
    decode_entry<true>(g + 768, r0, r1a, r1b, r2, rb1, rb2, rd, vd);
    int pa = atomicAdd(&lcur[ra >> CB_SHIFT], 1);
    int pb = atomicAdd(&lcur[rb >> CB_SHIFT], 1);
    int pc = atomicAdd(&lcur[rc >> CB_SHIFT], 1);
    int pd = atomicAdd(&lcur[rd >> CB_SHIFT], 1);
    stage[pa] = ((ra & rmask) << 20) | va;
    stage[pb] = ((rb & rmask) << 20) | vb;
    stage[pc] = ((rc & rmask) << 20) | vc;
    stage[pd] = ((rd & rmask) << 20) | vd;
  }
  for (; g < g1; g += 256) {
    int row, val;
    decode_entry<true>(g, r0, r1a, r1b, r2, rb1, rb2, row, val);
    int pos = atomicAdd(&lcur[row >> CB_SHIFT], 1);   // run is block-private
    stage[pos] = ((row & rmask) << 20) | val;
  }
}

// ---------- pass 3: per coarse-bucket: derive gscan locally + scatter pool slice ----------
// 1563 blocks x 512-row buckets, 4x-unrolled MLP, 4B packed stage entries.
__global__ __launch_bounds__(256) void fill_cb_kernel(
    const int* __restrict__ bhoff, const int* __restrict__ stage,
    int* __restrict__ gscan, int* __restrict__ pool) {
  __shared__ int hist[1 << CB_SHIFT];   // 512 row counters -> offsets -> cursors
  __shared__ int sums[256];
  const int cb = blockIdx.x;
  const int t = threadIdx.x;
  const int base_row = cb << CB_SHIFT;
  int nrows = CNT_TOT - base_row;
  if (nrows > (1 << CB_SHIFT)) nrows = 1 << CB_SHIFT;
  const int s0 = bhoff[cb * NBLK];
  const int s1 = bhoff[(cb + 1) * NBLK];   // bhoff[BH_N] = TOT_E covers cb == CB-1
  for (int i = t; i < (1 << CB_SHIFT); i += 256) hist[i] = 0;
  __syncthreads();
  {
    int i = s0 + t;
    for (; i + 768 < s1; i += 1024) {
      int ra = stage[i] >> 20, rb = stage[i + 256] >> 20,
          rc = stage[i + 512] >> 20, rd = stage[i + 768] >> 20;
      atomicAdd(&hist[ra], 1);
      atomicAdd(&hist[rb], 1);
      atomicAdd(&hist[rc], 1);
      atomicAdd(&hist[rd], 1);
    }
    for (; i < s1; i += 256) atomicAdd(&hist[stage[i] >> 20], 1);
  }
  __syncthreads();
  // exclusive scan of the 512 counts; thread t owns slots [2t, 2t+2)
  int loc[2];
  int sum = 0;
#pragma unroll
  for (int j = 0; j < 2; ++j) { loc[j] = sum; sum += hist[t * 2 + j]; }
  sums[t] = sum;
  __syncthreads();
  for (int off = 1; off < 256; off <<= 1) {
    int u = (t >= off) ? sums[t - off] : 0;
    __syncthreads();
    sums[t] += u;
    __syncthreads();
  }
  int pre = (t == 0) ? 0 : sums[t - 1];
#pragma unroll
  for (int j = 0; j < 2; ++j) hist[t * 2 + j] = s0 + pre + loc[j];   // row start offsets
  __syncthreads();
  for (int i = t; i < nrows; i += 256) gscan[base_row + i] = hist[i];
  if (cb == CB - 1 && t == 0) gscan[CNT_TOT] = TOT_E;
  __syncthreads();
  {
    int i = s0 + t;
    for (; i + 768 < s1; i += 1024) {
      int a = stage[i], b = stage[i + 256], c = stage[i + 512], d = stage[i + 768];
      int pa = atomicAdd(&hist[a >> 20], 1);
      int pb = atomicAdd(&hist[b >> 20], 1);
      int pc = atomicAdd(&hist[c >> 20], 1);
      int pd = atomicAdd(&hist[d >> 20], 1);
      pool[pa] = a & 0xFFFFF;
      pool[pb] = b & 0xFFFFF;
      pool[pc] = c & 0xFFFFF;
      pool[pd] = d & 0xFFFFF;
    }
    for (; i < s1; i += 256) {
      int rv = stage[i];
      int pos = atomicAdd(&hist[rv >> 20], 1);
      pool[pos] = rv & 0xFFFFF;   // slice is block-private: stays in one L2, written once
    }
  }
}

// ---------- SAT dual (L0, L2): 8 lanes per row, 4x-unrolled dual-table gather ----------
template <typename OutT>
__global__ __launch_bounds__(256) void sat_dual_z_kernel(
    const int* __restrict__ rowptr, const int* __restrict__ col,
    const float* __restrict__ ea, const __half* __restrict__ ha,
    const float* __restrict__ eb, const __half* __restrict__ hb,
    const float* __restrict__ pw, OutT* __restrict__ out, int n) {
  int row = blockIdx.x * 32 + (threadIdx.x >> 3);
  if (row >= n) return;
  int l8 = threadIdx.x & 7;
  const _Float16* haf = (const _Float16*)ha;
  const _Float16* hbf = (const _Float16*)hb;
  int p0 = rowptr[row], p1 = rowptr[row + 1];
  float za = 0.f, zb = 0.f;
  float aa[8], ab[8];
#pragma unroll
  for (int j = 0; j < 8; ++j) { aa[j] = 0.f; ab[j] = 0.f; }
  int p = p0;
  for (; p + 4 <= p1; p += 4) {
    int c0 = col[p], c1 = col[p + 1], c2 = col[p + 2], c3 = col[p + 3];
    float wa0 = ea[c0], wa1 = ea[c1], wa2 = ea[c2], wa3 = ea[c3];
    float wb0 = eb[c0], wb1 = eb[c1], wb2 = eb[c2], wb3 = eb[c3];
    f16x8 va0 = *(const f16x8*)(haf + ((long long)c0 << 6) + (l8 << 3));
    f16x8 va1 = *(const f16x8*)(haf + ((long long)c1 << 6) + (l8 << 3));
    f16x8 va2 = *(const f16x8*)(haf + ((long long)c2 << 6) + (l8 << 3));
    f16x8 va3 = *(const f16x8*)(haf + ((long long)c3 << 6) + (l8 << 3));
    f16x8 vb0 = *(const f16x8*)(hbf + ((long long)c0 << 6) + (l8 << 3));
    f16x8 vb1 = *(const f16x8*)(hbf + ((long long)c1 << 6) + (l8 << 3));
    f16x8 vb2 = *(const f16x8*)(hbf + ((long long)c2 << 6) + (l8 << 3));
    f16x8 vb3 = *(const f16x8*)(hbf + ((long long)c3 << 6) + (l8 << 3));
    za += (wa0 + wa1) + (wa2 + wa3);
    zb += (wb0 + wb1) + (wb2 + wb3);
#pragma unroll
    for (int j = 0; j < 8; ++j) {
      aa[j] += wa0 * (float)va0[j] + wa1 * (float)va1[j] + wa2 * (float)va2[j] + wa3 * (float)va3[j];
      ab[j] += wb0 * (float)vb0[j] + wb1 * (float)vb1[j] + wb2 * (float)vb2[j] + wb3 * (float)vb3[j];
    }
  }
  for (; p < p1; ++p) {
    int c = col[p];
    float wa = ea[c], wb = eb[c];
    f16x8 va = *(const f16x8*)(haf + ((long long)c << 6) + (l8 << 3));
    f16x8 vb = *(const f16x8*)(hbf + ((long long)c << 6) + (l8 << 3));
    za += wa;
    zb += wb;
#pragma unroll
    for (int j = 0; j < 8; ++j) {
      aa[j] += wa * (float)va[j];
      ab[j] += wb * (float)vb[j];
    }
  }
  float ia = za > 0.f ? 1.f / za : 0.f;
  float ib = zb > 0.f ? 1.f / zb : 0.f;
  float pv = pw[0];
  float r[8];
#pragma unroll
  for (int j = 0; j < 8; ++j) {
    float t = aa[j] * ia + ab[j] * ib;
    r[j] = t >= 0.f ? t : pv * t;   // prelu
  }
  if constexpr (sizeof(OutT) == 2) {
    f16x8 o;
#pragma unroll
    for (int j = 0; j < 8; ++j) o[j] = (_Float16)r[j];
    *(f16x8*)((_Float16*)out + (long long)row * 64 + (l8 << 3)) = o;
  } else {
    float* op = (float*)out + (long long)row * 64 + (l8 << 3);
    f32x4 o0 = {r[0], r[1], r[2], r[3]};
    f32x4 o1 = {r[4], r[5], r[6], r[7]};
    *(f32x4*)op = o0;
    *(f32x4*)(op + 4) = o1;
  }
}

// ---------- H2t = H2 @ triW via f16 MFMA ----------
__global__ __launch_bounds__(256) void tri_mfma_kernel(
    const __half* __restrict__ H2, const __half* __restrict__ Wt,
    __half* __restrict__ H2t, int n) {
  const int tid = threadIdx.x;
  const int m0 = blockIdx.x * 64;
  const int wave = tid >> 6;
  const int lane = tid & 63;
  const int quad = lane >> 4;
  const int l16 = lane & 15;
  const int arow = m0 + wave * 16 + l16;
  f32x4 acc[4];
#pragma unroll
  for (int i = 0; i < 4; ++i) acc[i] = (f32x4){0.f, 0.f, 0.f, 0.f};
  const f16x8* Wf = (const f16x8*)Wt;
#pragma unroll
  for (int kc = 0; kc < 2; ++kc) {
    f16x8 af = (f16x8){0, 0, 0, 0, 0, 0, 0, 0};
    if (arow < n) af = *(const f16x8*)((const _Float16*)H2 + (long long)arow * 64 + kc * 32 + quad * 8);
#pragma unroll
    for (int nb = 0; nb < 4; ++nb) {
      f16x8 bf = Wf[(kc * 4 + nb) * 64 + lane];
      acc[nb] = __builtin_amdgcn_mfma_f32_16x16x32_f16(af, bf, acc[nb], 0, 0, 0);
    }
  }
#pragma unroll
  for (int nb = 0; nb < 4; ++nb) {
    int col = nb * 16 + l16;
#pragma unroll
    for (int reg = 0; reg < 4; ++reg) {
      int rg = m0 + wave * 16 + quad * 4 + reg;
      if (rg < n) H2t[(long long)rg * 64 + col] = __float2half(acc[nb][reg]);
    }
  }
}

// ---------- mega edge-row kernel: G = prelu(satL1a + satL1b) + trib + B2 @ H2t ----------
// R5: heads a and b INTERLEAVED -- two independent gather chains per group (8 h-gathers
// in flight vs 4) instead of two sequential phases.  R4 counters: 3.0 TB/s = 48% of
// achievable random-gather BW, VALUBusy 41% -> residual MLP shortfall.
__global__ __launch_bounds__(256) void sat_l1_mega_kernel(
    const int* __restrict__ rp_a, const int* __restrict__ rp_b, const int* __restrict__ rp_B2,
    const int* __restrict__ pool,
    const float* __restrict__ ea, const __half* __restrict__ ha,
    const float* __restrict__ eb, const __half* __restrict__ hb,
    const __half* __restrict__ H2t, const float* __restrict__ trib,
    const float* __restrict__ pw, __half* __restrict__ G, int n) {
  int row = blockIdx.x * 32 + (threadIdx.x >> 3);
  if (row >= n) return;
  int l8 = threadIdx.x & 7;
  const _Float16* haf = (const _Float16*)ha;
  const _Float16* hbf = (const _Float16*)hb;
  const _Float16* h2f = (const _Float16*)H2t;
  float za = 0.f, zb = 0.f;
  float aa[8], ab[8];
#pragma unroll
  for (int j = 0; j < 8; ++j) { aa[j] = 0.f; ab[j] = 0.f; }
  int pa = rp_a[row], a1 = rp_a[row + 1];
  int pb = rp_b[row], b1 = rp_b[row + 1];
  // interleaved main loop: both heads issue 4 gathers each -> 8 lines in flight
  while (pa + 4 <= a1 && pb + 4 <= b1) {
    int ca0 = pool[pa], ca1 = pool[pa + 1], ca2 = pool[pa + 2], ca3 = pool[pa + 3];
    int cb0 = pool[pb], cb1 = pool[pb + 1], cb2 = pool[pb + 2], cb3 = pool[pb + 3];
    float wa0 = ea[ca0], wa1 = ea[ca1], wa2 = ea[ca2], wa3 = ea[ca3];
    float wb0 = eb[cb0], wb1 = eb[cb1], wb2 = eb[cb2], wb3 = eb[cb3];
    f16x8 va0 = *(const f16x8*)(haf + ((long long)ca0 << 6) + (l8 << 3));
    f16x8 va1 = *(const f16x8*)(haf + ((long long)ca1 << 6) + (l8 << 3));
    f16x8 va2 = *(const f16x8*)(haf + ((long long)ca2 << 6) + (l8 << 3));
    f16x8 va3 = *(const f16x8*)(haf + ((long long)ca3 << 6) + (l8 << 3));
    f16x8 vb0 = *(const f16x8*)(hbf + ((long long)cb0 << 6) + (l8 << 3));
    f16x8 vb1 = *(const f16x8*)(hbf + ((long long)cb1 << 6) + (l8 << 3));
    f16x8 vb2 = *(const f16x8*)(hbf + ((long long)cb2 << 6) + (l8 << 3));
    f16x8 vb3 = *(const f16x8*)(hbf + ((long long)cb3 << 6) + (l8 << 3));
    za += (wa0 + wa1) + (wa2 + wa3);
    zb += (wb0 + wb1) + (wb2 + wb3);
#pragma unroll
    for (int j = 0; j < 8; ++j) {
      aa[j] += wa0 * (float)va0[j] + wa1 * (float)va1[j] + wa2 * (float)va2[j] + wa3 * (float)va3[j];
      ab[j] += wb0 * (float)vb0[j] + wb1 * (float)vb1[j] + wb2 * (float)vb2[j] + wb3 * (float)vb3[j];
    }
    pa += 4;
    pb += 4;
  }
  // head a tail
  for (; pa + 4 <= a1; pa += 4) {
    int c0 = pool[pa], c1 = pool[pa + 1], c2 = pool[pa + 2], c3 = pool[pa + 3];
    float w0 = ea[c0], w1 = ea[c1], w2 = ea[c2], w3 = ea[c3];
    f16x8 v0 = *(const f16x8*)(haf + ((long long)c0 << 6) + (l8 << 3));
    f16x8 v1 = *(const f16x8*)(haf + ((long long)c1 << 6) + (l8 << 3));
    f16x8 v2 = *(const f16x8*)(haf + ((long long)c2 << 6) + (l8 << 3));
    f16x8 v3 = *(const f16x8*)(haf + ((long long)c3 << 6) + (l8 << 3));
    za += (w0 + w1) + (w2 + w3);
#pragma unroll
    for (int j = 0; j < 8; ++j)
      aa[j] += w0 * (float)v0[j] + w1 * (float)v1[j] + w2 * (float)v2[j] + w3 * (float)v3[j];
  }
  for (; pa < a1; ++pa) {
    int c = pool[pa];
    float w = ea[c];
    f16x8 v = *(const f16x8*)(haf + ((long long)c << 6) + (l8 << 3));
    za += w;
#pragma unroll
    for (int j = 0; j < 8; ++j) aa[j] += w * (float)v[j];
  }
  // head b tail
  for (; pb + 4 <= b1; pb += 4) {
    int c0 = pool[pb], c1 = pool[pb + 1], c2 = pool[pb + 2], c3 = pool[pb + 3];
    float w0 = eb[c0], w1 = eb[c1], w2 = eb[c2], w3 = eb[c3];
    f16x8 v0 = *(const f16x8*)(hbf + ((long long)c0 << 6) + (l8 << 3));
    f16x8 v1 = *(const f16x8*)(hbf + ((long long)c1 << 6) + (l8 << 3));
    f16x8 v2 = *(const f16x8*)(hbf + ((long long)c2 << 6) + (l8 << 3));
    f16x8 v3 = *(const f16x8*)(hbf + ((long long)c3 << 6) + (l8 << 3));
    zb += (w0 + w1) + (w2 + w3);
#pragma unroll
    for (int j = 0; j < 8; ++j)
      ab[j] += w0 * (float)v0[j] + w1 * (float)v1[j] + w2 * (float)v2[j] + w3 * (float)v3[j];
  }
  for (; pb < b1; ++pb) {
    int c = pool[pb];
    float w = eb[c];
    f16x8 v = *(const f16x8*)(hbf + ((long long)c << 6) + (l8 << 3));
    zb += w;
#pragma unroll
    for (int j = 0; j < 8; ++j) ab[j] += w * (float)v[j];
  }
  float ia = za > 0.f ? 1.f / za : 0.f;
  float ib = zb > 0.f ? 1.f / zb : 0.f;
  float pv = pw[0];
  float r[8];
#pragma unroll
  for (int j = 0; j < 8; ++j) {
    float t = aa[j] * ia + ab[j] * ib;
    r[j] = t >= 0.f ? t : pv * t;   // H1 = prelu(...)
  }
  // Tm = B2 @ H2t + trib (avg 1.5 entries/row; 2x unroll)
  float tm[8];
  {
    f32x4 t0 = *(const f32x4*)(trib + (l8 << 3));
    f32x4 t1 = *(const f32x4*)(trib + (l8 << 3) + 4);
#pragma unroll
    for (int j = 0; j < 4; ++j) { tm[j] = t0[j]; tm[j + 4] = t1[j]; }
  }
  {
    int p0 = rp_B2[row], p1 = rp_B2[row + 1];
    int p = p0;
    for (; p + 2 <= p1; p += 2) {
      int e0 = pool[p], e1 = pool[p + 1];
      int c0 = e0 / 3, c1 = e1 / 3;
      float s0 = (e0 - 3 * c0 == 1) ? -1.f : 1.f;
      float s1 = (e1 - 3 * c1 == 1) ? -1.f : 1.f;
      f16x8 v0 = *(const f16x8*)(h2f + ((long long)c0 << 6) + (l8 << 3));
      f16x8 v1 = *(const f16x8*)(h2f + ((long long)c1 << 6) + (l8 << 3));
#pragma unroll
      for (int j = 0; j < 8; ++j) tm[j] += s0 * (float)v0[j] + s1 * (float)v1[j];
    }
    for (; p < p1; ++p) {
      int e = pool[p];
      int c = e / 3;
      float s = (e - 3 * c == 1) ? -1.f : 1.f;
      f16x8 v = *(const f16x8*)(h2f + ((long long)c << 6) + (l8 << 3));
#pragma unroll
      for (int j = 0; j < 8; ++j) tm[j] += s * (float)v[j];
    }
  }
  f16x8 o;
#pragma unroll
  for (int j = 0; j < 8; ++j) o[j] = (_Float16)(r[j] + tm[j]);
  *(f16x8*)((_Float16*)G + (long long)row * 64 + (l8 << 3)) = o;
}

// ---------- out = (H0 + B1 @ G) / 3, 8 lanes per row, B1 loop 8x unrolled ----------
__global__ __launch_bounds__(256) void final_kernel(
    const int* __restrict__ rowptr, const int* __restrict__ ent,
    const float* __restrict__ H0, const __half* __restrict__ G,
    float* __restrict__ out, int n) {
  int row = blockIdx.x * 32 + (threadIdx.x >> 3);
  if (row >= n) return;
  int l8 = threadIdx.x & 7;
  const _Float16* gf = (const _Float16*)G;
  float acc[8];
  {
    const float* hp = H0 + (long long)row * 64 + (l8 << 3);
    f32x4 a0 = *(const f32x4*)hp;
    f32x4 a1 = *(const f32x4*)(hp + 4);
#pragma unroll
    for (int j = 0; j < 4; ++j) { acc[j] = a0[j]; acc[j + 4] = a1[j]; }
  }
  int p0 = rowptr[row], p1 = rowptr[row + 1];
  int p = p0;
  for (; p + 8 <= p1; p += 8) {
    int e[8];
#pragma unroll
    for (int k = 0; k < 8; ++k) e[k] = ent[p + k];
    f16x8 v[8];
#pragma unroll
    for (int k = 0; k < 8; ++k)
      v[k] = *(const f16x8*)(gf + ((long long)(e[k] >> 1) << 6) + (l8 << 3));
#pragma unroll
    for (int k = 0; k < 8; ++k) {
      float s = (e[k] & 1) ? -1.f : 1.f;
#pragma unroll
      for (int j = 0; j < 8; ++j) acc[j] += s * (float)v[k][j];
    }
  }
  for (; p + 4 <= p1; p += 4) {
    int e0 = ent[p], e1 = ent[p + 1], e2 = ent[p + 2], e3 = ent[p + 3];
    float s0 = (e0 & 1) ? -1.f : 1.f;
    float s1 = (e1 & 1) ? -1.f : 1.f;
    float s2 = (e2 & 1) ? -1.f : 1.f;
    float s3 = (e3 & 1) ? -1.f : 1.f;
    f16x8 v0 = *(const f16x8*)(gf + ((long long)(e0 >> 1) << 6) + (l8 << 3));
    f16x8 v1 = *(const f16x8*)(gf + ((long long)(e1 >> 1) << 6) + (l8 << 3));
    f16x8 v2 = *(const f16x8*)(gf + ((long long)(e2 >> 1) << 6) + (l8 << 3));
    f16x8 v3 = *(const f16x8*)(gf + ((long long)(e3 >> 1) << 6) + (l8 << 3));
#pragma unroll
    for (int j = 0; j < 8; ++j)
      acc[j] += s0 * (float)v0[j] + s1 * (float)v1[j] + s2 * (float)v2[j] + s3 * (float)v3[j];
  }
  for (; p < p1; ++p) {
    int e = ent[p];
    float s = (e & 1) ? -1.f : 1.f;
    f16x8 v = *(const f16x8*)(gf + ((long long)(e >> 1) << 6) + (l8 << 3));
#pragma unroll
    for (int j = 0; j < 8; ++j) acc[j] += s * (float)v[j];
  }
  float* op = out + (long long)row * 64 + (l8 << 3);
  f32x4 o0 = {acc[0] * (1.0f / 3.0f), acc[1] * (1.0f / 3.0f), acc[2] * (1.0f / 3.0f), acc[3] * (1.0f / 3.0f)};
  f32x4 o1 = {acc[4] * (1.0f / 3.0f), acc[5] * (1.0f / 3.0f), acc[6] * (1.0f / 3.0f), acc[7] * (1.0f / 3.0f)};
  *(f32x4*)op = o0;
  *(f32x4*)(op + 4) = o1;
}

extern "C" void kernel_launch(void* const* d_in, const int* in_sizes, int n_in,
                              void* d_out, int out_size, void* d_ws, size_t ws_size,
                              hipStream_t stream) {
  const float* X0 = (const float*)d_in[0];
  const int* E1 = (const int*)d_in[1];
  const int* T2 = (const int*)d_in[2];
  const int* L0i = (const int*)d_in[3];
  const int* L1ai = (const int*)d_in[4];
  const int* L1bi = (const int*)d_in[5];
  const int* L2i = (const int*)d_in[6];
  const int* B1i = (const int*)d_in[7];
  const int* B2i = (const int*)d_in[9];
  const float* W = (const float*)d_in[11];
  const float* bvec = (const float*)d_in[12];
  // a1_w/a1_b are mathematically dead: s1[r] cancels in the row softmax.
  const float* a2w = (const float*)d_in[15];
  const float* a2b = (const float*)d_in[16];
  const float* pw = (const float*)d_in[17];
  const float* triW = (const float*)d_in[18];
  const float* trib = (const float*)d_in[19];
  float* out = (float*)d_out;

  char* base = (char*)d_ws;
  size_t off = 0;
  auto alloc = [&](size_t bytes) -> void* {
    void* p = base + off;
    off += (bytes + 255) & ~(size_t)255;
    return p;
  };
  unsigned int* Xbit = (unsigned int*)alloc((size_t)N0 * 16 * 4);
  unsigned short* Bp = (unsigned short*)alloc((size_t)3 * 65536 * 2);
  __half* Wt = (__half*)alloc((size_t)4096 * 2);
  __half* h0 = (__half*)alloc((size_t)N0 * 64 * 2);
  __half* h1 = (__half*)alloc((size_t)N0 * 64 * 2);
  __half* h2 = (__half*)alloc((size_t)N1 * 64 * 2);
  __half* h3 = (__half*)alloc((size_t)N1 * 64 * 2);
  __half* h4 = (__half*)alloc((size_t)N2 * 64 * 2);
  __half* h5 = (__half*)alloc((size_t)N2 * 64 * 2);
  float* e0 = (float*)alloc((size_t)N0 * 4);
  float* e1 = (float*)alloc((size_t)N0 * 4);
  float* e2 = (float*)alloc((size_t)N1 * 4);
  float* e3 = (float*)alloc((size_t)N1 * 4);
  float* e4 = (float*)alloc((size_t)N2 * 4);
  float* e5 = (float*)alloc((size_t)N2 * 4);
  float* H0 = (float*)alloc((size_t)N0 * 64 * 4);
  __half* H2 = (__half*)alloc((size_t)N2 * 64 * 2);
  __half* H2t = (__half*)alloc((size_t)N2 * 64 * 2);
  __half* G = (__half*)alloc((size_t)N1 * 64 * 2);
  int* gscan = (int*)alloc((size_t)(CNT_TOT + 1) * 4);
  int* pool = (int*)alloc((size_t)TOT_E * 4);
  int* stage = (int*)alloc((size_t)TOT_E * 4);
  int* bh = (int*)alloc((size_t)BH_N * 4);
  int* bhoff = (int*)alloc((size_t)(BH_N + 1) * 4);
  int* bsum = (int*)alloc((size_t)(BH_SCAN_BLOCKS + 1) * 4);

  pack_bits_kernel<<<(N0 + 3) / 4, 256, 0, stream>>>(X0, Xbit);
  pack_w_kernel<<<(3 * 65536 + 255) / 256, 256, 0, stream>>>(W, Bp);
  pack_wt_kernel<<<16, 256, 0, stream>>>(triW, Wt);

  gemm_sat_kernel<1><<<(N0 + 127) / 128, 256, 0, stream>>>(Xbit, nullptr, Bp, bvec, a2w, a2b, 0, N0, h0, h1, e0, e1);
  gemm_sat_kernel<2><<<(N1 + 127) / 128, 256, 0, stream>>>(Xbit, E1, Bp + 65536, bvec, a2w, a2b, 2, N1, h2, h3, e2, e3);
  gemm_sat_kernel<3><<<(N2 + 127) / 128, 256, 0, stream>>>(Xbit, T2, Bp + 2 * 65536, bvec, a2w, a2b, 4, N2, h4, h5, e4, e5);

  // radix-partition CSR build (no row-level global histogram needed)
  blkhist_kernel<<<NBLK, 256, 0, stream>>>(L0i, L1ai, L1bi, L2i, B1i, B2i, bh);
  scan_partial_kernel<<<BH_SCAN_BLOCKS, 256, 0, stream>>>(bh, bsum, BH_N);
  scan_bsum_kernel<<<1, 256, 0, stream>>>(bsum, BH_SCAN_BLOCKS);
  scan_write_kernel<<<BH_SCAN_BLOCKS, 256, 0, stream>>>(bh, bsum, bhoff, BH_N, BH_SCAN_BLOCKS);
  stage_part_kernel<<<NBLK, 256, 0, stream>>>(L0i, L1ai, L1bi, L2i, B1i, B2i, bhoff, stage);
  fill_cb_kernel<<<CB, 256, 0, stream>>>(bhoff, stage, gscan, pool);

  const int* rp0 = gscan + SEG_L0;
  const int* rp1a = gscan + SEG_L1A;
  const int* rp1b = gscan + SEG_L1B;
  const int* rp2 = gscan + SEG_L2;
  const int* rpB1 = gscan + SEG_B1;
  const int* rpB2 = gscan + SEG_B2;

  sat_dual_z_kernel<float><<<(N0 + 31) / 32, 256, 0, stream>>>(rp0, pool, e0, h0, e1, h1, pw, H0, N0);
  sat_dual_z_kernel<__half><<<(N2 + 31) / 32, 256, 0, stream>>>(rp2, pool, e4, h4, e5, h5, pw, H2, N2);
  tri_mfma_kernel<<<(N2 + 63) / 64, 256, 0, stream>>>(H2, Wt, H2t, N2);
  sat_l1_mega_kernel<<<(N1 + 31) / 32, 256, 0, stream>>>(rp1a, rp1b, rpB2, pool, e2, h2, e3, h3,
                                                         H2t, trib, pw, G, N1);
  final_kernel<<<(N0 + 31) / 32, 256, 0, stream>>>(rpB1, pool, H0, G, out, N0);
}

// Round 6
// 561.637 us; speedup vs baseline: 1.0322x; 1.0322x over previous
//
#include <hip/hip_runtime.h>
#include <hip/hip_fp16.h>

static constexpr int N0 = 50000;
static constexpr int N1 = 200000;
static constexpr int N2 = 100000;
static constexpr int NNZ0 = 600000;
static constexpr int NNZ1 = 1000000;
static constexpr int NNZ2 = 600000;
static constexpr int FIN = 500;

// concatenated count layout: [L0 | L1a | L1b | L2 | B1 | B2]
static constexpr int SEG_L0 = 0;
static constexpr int SEG_L1A = 50000;
static constexpr int SEG_L1B = 250000;
static constexpr int SEG_L2 = 450000;
static constexpr int SEG_B1 = 550000;
static constexpr int SEG_B2 = 600000;
static constexpr int CNT_TOT = 800000;
static constexpr int TOT_E = NNZ0 + NNZ1 + NNZ1 + NNZ2 + 2 * N1 + 3 * N2;  // 3.9M
// radix partition: 512 partition blocks x 1563 coarse buckets (512 rows each).
static constexpr int NBLK = 512;
static constexpr int EPB = (TOT_E + NBLK - 1) / NBLK;        // 7618 entries/block
static constexpr int CB_SHIFT = 9;                           // 512 rows per coarse bucket
static constexpr int CB = (CNT_TOT + (1 << CB_SHIFT) - 1) >> CB_SHIFT;  // 1563
static constexpr int BH_N = CB * NBLK;                       // 800256
static constexpr int SCAN_CHUNK = 4096;
static constexpr int BH_SCAN_BLOCKS = (BH_N + SCAN_CHUNK - 1) / SCAN_CHUNK;  // 196 (<=256 cap)

typedef __attribute__((ext_vector_type(8))) short bf16x8;
typedef __attribute__((ext_vector_type(8))) _Float16 f16x8;
typedef __attribute__((ext_vector_type(4))) float f32x4;

typedef const unsigned int __attribute__((address_space(1)))* gas_u32p;
typedef unsigned int __attribute__((address_space(3)))* las_u32p;

__device__ __forceinline__ unsigned short f2bf(float f) {
  unsigned int b = __float_as_uint(f);
  b = (b + 0x7FFFu + ((b >> 16) & 1u)) >> 16;   // RNE
  return (unsigned short)b;
}

// ---------- pack X0 -> binary bitmasks: 512 bits = 16 uints per row (3.2 MB, L2-resident) ----------
__global__ __launch_bounds__(256) void pack_bits_kernel(const float* __restrict__ X0,
                                                        unsigned int* __restrict__ Xbit) {
  int row = blockIdx.x * 4 + (threadIdx.x >> 6);
  if (row >= N0) return;
  int lane = threadIdx.x & 63;
  const float* xr = X0 + (long long)row * FIN;
#pragma unroll
  for (int i = 0; i < 8; ++i) {
    int c = i * 64 + lane;
    bool pred = (c < FIN) && (xr[c] != 0.0f);
    unsigned long long m = __ballot(pred);
    if (lane == 0) {
      Xbit[row * 16 + 2 * i] = (unsigned int)m;
      Xbit[row * 16 + 2 * i + 1] = (unsigned int)(m >> 32);
    }
  }
}

// ---------- pack W -> bf16 MFMA B-fragment layout: [level][kc][nb][lane][j] ----------
__global__ void pack_w_kernel(const float* __restrict__ W, unsigned short* __restrict__ Bp) {
  int g = blockIdx.x * 256 + threadIdx.x;
  if (g >= 3 * 65536) return;
  int j = g & 7;
  int lane = (g >> 3) & 63;
  int nb = (g >> 9) & 7;
  int kc = (g >> 12) & 15;
  int level = g >> 16;
  int k = kc * 32 + (lane >> 4) * 8 + j;
  int col128 = nb * 16 + (lane & 15);
  int head = level * 2 + (col128 >> 6);
  int col = col128 & 63;
  float f = 0.0f;
  if (k < FIN) f = W[((long long)head * FIN + k) * 64 + col];
  Bp[g] = f2bf(f);
}

// ---------- pack triW -> f16 B-fragment layout: [kc(2)][nb(4)][lane][j] ----------
__global__ void pack_wt_kernel(const float* __restrict__ triW, __half* __restrict__ Wt) {
  int g = blockIdx.x * 256 + threadIdx.x;
  if (g >= 4096) return;
  int j = g & 7;
  int lane = (g >> 3) & 63;
  int nb = (g >> 9) & 3;
  int kc = g >> 11;
  int k = kc * 32 + (lane >> 4) * 8 + j;
  int col = nb * 16 + (lane & 15);
  Wt[g] = __float2half(triW[k * 64 + col]);
}

// ---------- fused bit-gather(AND) + in-register bf16 expansion + MFMA ----------
// B-fragments staged into LDS via global_load_lds (zero VGPR cost), double-buffered,
// one raw barrier per kc (R3: fixed register-starvation VMEM serialization).
template <int NSRC>
__global__ __launch_bounds__(256, 4) void gemm_sat_kernel(
    const unsigned int* __restrict__ Xbit, const int* __restrict__ srcidx,
    const unsigned short* __restrict__ Bp, const float* __restrict__ bvec,
    const float* __restrict__ a2w, const float* __restrict__ a2b, int head_lo,
    int M, __half* __restrict__ h_lo, __half* __restrict__ h_hi,
    float* __restrict__ e_lo, float* __restrict__ e_hi) {
  __shared__ __align__(16) unsigned int Sb[128 * 20];
  __shared__ __align__(16) unsigned short Bs[2][4096];   // 2 x 8KB double buffer
  const int tid = threadIdx.x;
  const int m0 = blockIdx.x * 128;
  const int wave = tid >> 6;
  const int lane = tid & 63;
  {
    // 2 threads per row: thread handles uint4 chunks {2*hf, 2*hf+1} of the 64B row mask
    int rg = m0 + (tid >> 1);
    int hf = tid & 1;
    uint4 a[2];
#pragma unroll
    for (int c2 = 0; c2 < 2; ++c2) a[c2] = make_uint4(0u, 0u, 0u, 0u);
    if (rg < M) {
      if (NSRC == 1) {
        const uint4* up = (const uint4*)(Xbit + (long long)rg * 16);
#pragma unroll
        for (int c2 = 0; c2 < 2; ++c2) a[c2] = up[hf * 2 + c2];
      } else if (NSRC == 2) {
        const uint4* up = (const uint4*)(Xbit + (long long)srcidx[2 * rg + 0] * 16);
        const uint4* vp = (const uint4*)(Xbit + (long long)srcidx[2 * rg + 1] * 16);
#pragma unroll
        for (int c2 = 0; c2 < 2; ++c2) {
          uint4 u = up[hf * 2 + c2], v = vp[hf * 2 + c2];
          a[c2] = make_uint4(u.x & v.x, u.y & v.y, u.z & v.z, u.w & v.w);
        }
      } else {
        const uint4* up = (const uint4*)(Xbit + (long long)srcidx[3 * rg + 0] * 16);
        const uint4* vp = (const uint4*)(Xbit + (long long)srcidx[3 * rg + 1] * 16);
        const uint4* wp = (const uint4*)(Xbit + (long long)srcidx[3 * rg + 2] * 16);
#pragma unroll
        for (int c2 = 0; c2 < 2; ++c2) {
          uint4 u = up[hf * 2 + c2], v = vp[hf * 2 + c2], w = wp[hf * 2 + c2];
          a[c2] = make_uint4(u.x & v.x & w.x, u.y & v.y & w.y, u.z & v.z & w.z, u.w & v.w & w.w);
        }
      }
    }
#pragma unroll
    for (int c2 = 0; c2 < 2; ++c2)
      *(uint4*)(Sb + (tid >> 1) * 20 + (hf * 2 + c2) * 4) = a[c2];
  }

  // stage B slab for kc (8KB = 4 waves x 2 instrs x 1KB) direct to LDS, no VGPR round-trip.
  auto stageB = [&](int buf, int kc2) {
    int chunk0 = wave * 2;
    const unsigned short* g0 = Bp + kc2 * 4096 + chunk0 * 512 + lane * 8;
    __builtin_amdgcn_global_load_lds((gas_u32p)(const void*)g0,
                                     (las_u32p)(void*)&Bs[buf][chunk0 * 512], 16, 0, 0);
    __builtin_amdgcn_global_load_lds((gas_u32p)(const void*)(g0 + 512),
                                     (las_u32p)(void*)&Bs[buf][chunk0 * 512 + 512], 16, 0, 0);
  };
  stageB(0, 0);
  __syncthreads();   // full drain once: Sb writes + Bs[0] stage complete

  const int quad = lane >> 4;
  const int l16 = lane & 15;
  f32x4 acc[8][2];   // [nb][sub]
#pragma unroll
  for (int i = 0; i < 8; ++i)
#pragma unroll
    for (int s = 0; s < 2; ++s) acc[i][s] = (f32x4){0.f, 0.f, 0.f, 0.f};

  for (int kc = 0; kc < 16; ++kc) {
    const int cur = kc & 1;
    if (kc < 15) stageB(cur ^ 1, kc + 1);   // issue next stage first (overlaps compute)
    bf16x8 af[2];
#pragma unroll
    for (int sub = 0; sub < 2; ++sub) {
      unsigned int bw = Sb[(wave * 32 + sub * 16 + l16) * 20 + kc];
      unsigned int byte = (bw >> (quad * 8)) & 0xFFu;
#pragma unroll
      for (int j = 0; j < 4; ++j) {
        unsigned int b2 = (byte >> (2 * j)) & 3u;
        ((unsigned int*)&af[sub])[j] = ((b2 & 1u) | ((b2 & 2u) << 15)) * 0x3F80u;
      }
    }
#pragma unroll
    for (int nb = 0; nb < 8; ++nb) {
      bf16x8 bf = *(const bf16x8*)&Bs[cur][(nb * 64 + lane) * 8];
#pragma unroll
      for (int sub = 0; sub < 2; ++sub)
        acc[nb][sub] = __builtin_amdgcn_mfma_f32_16x16x32_bf16(af[sub], bf, acc[nb][sub], 0, 0, 0);
    }
    if (kc < 15) {
      asm volatile("s_waitcnt vmcnt(0)" ::: "memory");   // next stage landed
      __builtin_amdgcn_sched_barrier(0);
      __builtin_amdgcn_s_barrier();                       // raw barrier: no lgkm/vm drain churn
    }
  }

  float bia[8], aw[8];
#pragma unroll
  for (int nb = 0; nb < 8; ++nb) {
    int col128 = nb * 16 + l16;
    int hh = col128 >> 6, col = col128 & 63;
    bia[nb] = bvec[(head_lo + hh) * 64 + col];
    aw[nb] = a2w[(head_lo + hh) * 64 + col];
  }
  float blo = a2b[head_lo], bhi = a2b[head_lo + 1];
#pragma unroll
  for (int sub = 0; sub < 2; ++sub) {
    float plo[4] = {0.f, 0.f, 0.f, 0.f};
    float phi[4] = {0.f, 0.f, 0.f, 0.f};
#pragma unroll
    for (int nb = 0; nb < 8; ++nb) {
      int col128 = nb * 16 + l16;
      int hh = col128 >> 6, col = col128 & 63;
      __half* hdst = hh ? h_hi : h_lo;
#pragma unroll
      for (int reg = 0; reg < 4; ++reg) {
        int rg = m0 + wave * 32 + sub * 16 + quad * 4 + reg;   // C/D: row=quad*4+reg, col=l16
        float v = acc[nb][sub][reg] + bia[nb];
        if (rg < M) hdst[(long long)rg * 64 + col] = __float2half(v);
        if (hh) phi[reg] += v * aw[nb]; else plo[reg] += v * aw[nb];
      }
    }
#pragma unroll
    for (int off = 1; off < 16; off <<= 1) {
#pragma unroll
      for (int reg = 0; reg < 4; ++reg) {
        plo[reg] += __shfl_xor(plo[reg], off);
        phi[reg] += __shfl_xor(phi[reg], off);
      }
    }
    if (l16 == 0) {
#pragma unroll
      for (int reg = 0; reg < 4; ++reg) {
        int rg = m0 + wave * 32 + sub * 16 + quad * 4 + reg;
        if (rg < M) {
          e_lo[rg] = __expf(plo[reg] + blo);   // |s2| small by construction: no max needed
          e_hi[rg] = __expf(phi[reg] + bhi);
        }
      }
    }
  }
}

// ---------- entry decode shared by partition passes ----------
template <bool NEED_VAL>
__device__ __forceinline__ void decode_entry(
    int g, const int* __restrict__ r0, const int* __restrict__ r1a,
    const int* __restrict__ r1b, const int* __restrict__ r2,
    const int* __restrict__ rb1, const int* __restrict__ rb2, int& row, int& val) {
  if (g < 600000) { int l = g; row = SEG_L0 + r0[l]; if (NEED_VAL) val = r0[NNZ0 + l]; }
  else if (g < 1600000) { int l = g - 600000; row = SEG_L1A + r1a[l]; if (NEED_VAL) val = r1a[NNZ1 + l]; }
  else if (g < 2600000) { int l = g - 1600000; row = SEG_L1B + r1b[l]; if (NEED_VAL) val = r1b[NNZ1 + l]; }
  else if (g < 3200000) { int l = g - 2600000; row = SEG_L2 + r2[l]; if (NEED_VAL) val = r2[NNZ2 + l]; }
  else if (g < 3600000) { int l = g - 3200000; row = SEG_B1 + rb1[l]; val = l; }   // B1: entry id
  else { int l = g - 3600000; row = SEG_B2 + rb2[l]; val = l; }                    // B2: entry id
}

// ---------- pass 1: per-(block, coarse-bucket) histogram via LDS, 4x-unrolled MLP ----------
__global__ __launch_bounds__(256) void blkhist_kernel(
    const int* __restrict__ r0, const int* __restrict__ r1a, const int* __restrict__ r1b,
    const int* __restrict__ r2, const int* __restrict__ rb1, const int* __restrict__ rb2,
    int* __restrict__ bh) {
  __shared__ int hcnt[CB];
  int blk = blockIdx.x;
  for (int i = threadIdx.x; i < CB; i += 256) hcnt[i] = 0;
  __syncthreads();
  int g0 = blk * EPB;
  int g1 = g0 + EPB; if (g1 > TOT_E) g1 = TOT_E;
  int g = g0 + threadIdx.x;
  for (; g + 768 < g1; g += 1024) {
    int ra, rb, rc, rd, v;
    decode_entry<false>(g, r0, r1a, r1b, r2, rb1, rb2, ra, v);
    decode_entry<false>(g + 256, r0, r1a, r1b, r2, rb1, rb2, rb, v);
    decode_entry<false>(g + 512, r0, r1a, r1b, r2, rb1, rb2, rc, v);
    decode_entry<false>(g + 768, r0, r1a, r1b, r2, rb1, rb2, rd, v);
    atomicAdd(&hcnt[ra >> CB_SHIFT], 1);
    atomicAdd(&hcnt[rb >> CB_SHIFT], 1);
    atomicAdd(&hcnt[rc >> CB_SHIFT], 1);
    atomicAdd(&hcnt[rd >> CB_SHIFT], 1);
  }
  for (; g < g1; g += 256) {
    int row, val;
    decode_entry<false>(g, r0, r1a, r1b, r2, rb1, rb2, row, val);
    atomicAdd(&hcnt[row >> CB_SHIFT], 1);
  }
  __syncthreads();
  for (int i = threadIdx.x; i < CB; i += 256) bh[i * NBLK + blk] = hcnt[i];
}

// ---------- 3-phase scan (parameterized size) ----------
__global__ __launch_bounds__(256) void scan_partial_kernel(const int* __restrict__ cnt,
                                                           int* __restrict__ bsum, int n) {
  __shared__ int s[256];
  int b = blockIdx.x, t = threadIdx.x;
  int base = b * SCAN_CHUNK + t * 16;
  int sum = 0;
#pragma unroll
  for (int i = 0; i < 16; ++i) {
    int idx = base + i;
    if (idx < n) sum += cnt[idx];
  }
  s[t] = sum;
  __syncthreads();
  for (int off = 128; off > 0; off >>= 1) {
    if (t < off) s[t] += s[t + off];
    __syncthreads();
  }
  if (t == 0) bsum[b] = s[0];
}

__global__ __launch_bounds__(256) void scan_bsum_kernel(int* __restrict__ bsum, int nb) {
  __shared__ int s[256];
  int t = threadIdx.x;
  int v = (t < nb) ? bsum[t] : 0;
  s[t] = v;
  __syncthreads();
  for (int off = 1; off < 256; off <<= 1) {
    int u = (t >= off) ? s[t - off] : 0;
    __syncthreads();
    s[t] += u;
    __syncthreads();
  }
  if (t < nb) bsum[t] = (t == 0) ? 0 : s[t - 1];
  if (t == 0) bsum[nb] = s[nb - 1];
}

__global__ __launch_bounds__(256) void scan_write_kernel(const int* __restrict__ cnt,
                                                         const int* __restrict__ bsum,
                                                         int* __restrict__ gout, int n, int nb) {
  __shared__ int s[256];
  int b = blockIdx.x, t = threadIdx.x;
  int base = b * SCAN_CHUNK + t * 16;
  int loc[16];
  int sum = 0;
#pragma unroll
  for (int i = 0; i < 16; ++i) {
    int idx = base + i;
    int v = (idx < n) ? cnt[idx] : 0;
    loc[i] = sum;
    sum += v;
  }
  s[t] = sum;
  __syncthreads();
  for (int off = 1; off < 256; off <<= 1) {
    int u = (t >= off) ? s[t - off] : 0;
    __syncthreads();
    s[t] += u;
    __syncthreads();
  }
  int toff = bsum[b] + ((t == 0) ? 0 : s[t - 1]);
#pragma unroll
  for (int i = 0; i < 16; ++i) {
    int idx = base + i;
    if (idx < n) gout[idx] = toff + loc[i];
  }
  if (b == 0 && t == 0) gout[n] = bsum[nb];
}

// ---------- pass 2: write packed (row_lo,val) into block-PRIVATE per-bucket runs, 4x MLP ----------
// stage entry packed to 4B -- within a bucket only row&511 (9b) + val (<=20b) needed.
__global__ __launch_bounds__(256) void stage_part_kernel(
    const int* __restrict__ r0, const int* __restrict__ r1a, const int* __restrict__ r1b,
    const int* __restrict__ r2, const int* __restrict__ rb1, const int* __restrict__ rb2,
    const int* __restrict__ bhoff, int* __restrict__ stage) {
  __shared__ int lcur[CB];
  int blk = blockIdx.x;
  for (int i = threadIdx.x; i < CB; i += 256) lcur[i] = bhoff[i * NBLK + blk];
  __syncthreads();
  int g0 = blk * EPB;
  int g1 = g0 + EPB; if (g1 > TOT_E) g1 = TOT_E;
  const int rmask = (1 << CB_SHIFT) - 1;
  int g = g0 + threadIdx.x;
  for (; g + 768 < g1; g += 1024) {
    int ra, rb, rc, rd, va, vb, vc, vd;
    decode_entry<true>(g, r0, r1a, r1b, r2, rb1, rb2, ra, va);
    decode_entry<true>(g + 256, r0, r1a, r1b, r2, rb1, rb2, rb, vb);
    decode_entry<true>(g + 512, r0, r1a, r1b, r2, rb1, rb2, rc, vc);
    decode_entry<true>(g + 768, r0, r1a, r1b, r2, rb1, rb2, rd, vd);
    int pa = atomicAdd(&lcur[ra >> CB_SHIFT], 1);
    int pb = atomicAdd(&lcur[rb >> CB_SHIFT], 1);
    int pc = atomicAdd(&lcur[rc >> CB_SHIFT], 1);
    int pd = atomicAdd(&lcur[rd >> CB_SHIFT], 1);
    stage[pa] = ((ra & rmask) << 20) | va;
    stage[pb] = ((rb & rmask) << 20) | vb;
    stage[pc] = ((rc & rmask) << 20) | vc;
    stage[pd] = ((rd & rmask) << 20) | vd;
  }
  for (; g < g1; g += 256) {
    int row, val;
    decode_entry<true>(g, r0, r1a, r1b, r2, rb1, rb2, row, val);
    int pos = atomicAdd(&lcur[row >> CB_SHIFT], 1);   // run is block-private
    stage[pos] = ((row & rmask) << 20) | val;
  }
}

// ---------- pass 3: per coarse-bucket: derive gscan locally + scatter pool slice ----------
// 1563 blocks x 512-row buckets, 4x-unrolled MLP, 4B packed stage entries.
__global__ __launch_bounds__(256) void fill_cb_kernel(
    const int* __restrict__ bhoff, const int* __restrict__ stage,
    int* __restrict__ gscan, int* __restrict__ pool) {
  __shared__ int hist[1 << CB_SHIFT];   // 512 row counters -> offsets -> cursors
  __shared__ int sums[256];
  const int cb = blockIdx.x;
  const int t = threadIdx.x;
  const int base_row = cb << CB_SHIFT;
  int nrows = CNT_TOT - base_row;
  if (nrows > (1 << CB_SHIFT)) nrows = 1 << CB_SHIFT;
  const int s0 = bhoff[cb * NBLK];
  const int s1 = bhoff[(cb + 1) * NBLK];   // bhoff[BH_N] = TOT_E covers cb == CB-1
  for (int i = t; i < (1 << CB_SHIFT); i += 256) hist[i] = 0;
  __syncthreads();
  {
    int i = s0 + t;
    for (; i + 768 < s1; i += 1024) {
      int ra = stage[i] >> 20, rb = stage[i + 256] >> 20,
          rc = stage[i + 512] >> 20, rd = stage[i + 768] >> 20;
      atomicAdd(&hist[ra], 1);
      atomicAdd(&hist[rb], 1);
      atomicAdd(&hist[rc], 1);
      atomicAdd(&hist[rd], 1);
    }
    for (; i < s1; i += 256) atomicAdd(&hist[stage[i] >> 20], 1);
  }
  __syncthreads();
  // exclusive scan of the 512 counts; thread t owns slots [2t, 2t+2)
  int loc[2];
  int sum = 0;
#pragma unroll
  for (int j = 0; j < 2; ++j) { loc[j] = sum; sum += hist[t * 2 + j]; }
  sums[t] = sum;
  __syncthreads();
  for (int off = 1; off < 256; off <<= 1) {
    int u = (t >= off) ? sums[t - off] : 0;
    __syncthreads();
    sums[t] += u;
    __syncthreads();
  }
  int pre = (t == 0) ? 0 : sums[t - 1];
#pragma unroll
  for (int j = 0; j < 2; ++j) hist[t * 2 + j] = s0 + pre + loc[j];   // row start offsets
  __syncthreads();
  for (int i = t; i < nrows; i += 256) gscan[base_row + i] = hist[i];
  if (cb == CB - 1 && t == 0) gscan[CNT_TOT] = TOT_E;
  __syncthreads();
  {
    int i = s0 + t;
    for (; i + 768 < s1; i += 1024) {
      int a = stage[i], b = stage[i + 256], c = stage[i + 512], d = stage[i + 768];
      int pa = atomicAdd(&hist[a >> 20], 1);
      int pb = atomicAdd(&hist[b >> 20], 1);
      int pc = atomicAdd(&hist[c >> 20], 1);
      int pd = atomicAdd(&hist[d >> 20], 1);
      pool[pa] = a & 0xFFFFF;
      pool[pb] = b & 0xFFFFF;
      pool[pc] = c & 0xFFFFF;
      pool[pd] = d & 0xFFFFF;
    }
    for (; i < s1; i += 256) {
      int rv = stage[i];
      int pos = atomicAdd(&hist[rv >> 20], 1);
      pool[pos] = rv & 0xFFFFF;   // slice is block-private: stays in one L2, written once
    }
  }
}

// ---------- SAT dual (L0, L2): 8 lanes per row, 4x-unrolled dual-table gather ----------
template <typename OutT>
__global__ __launch_bounds__(256) void sat_dual_z_kernel(
    const int* __restrict__ rowptr, const int* __restrict__ col,
    const float* __restrict__ ea, const __half* __restrict__ ha,
    const float* __restrict__ eb, const __half* __restrict__ hb,
    const float* __restrict__ pw, OutT* __restrict__ out, int n) {
  int row = blockIdx.x * 32 + (threadIdx.x >> 3);
  if (row >= n) return;
  int l8 = threadIdx.x & 7;
  const _Float16* haf = (const _Float16*)ha;
  const _Float16* hbf = (const _Float16*)hb;
  int p0 = rowptr[row], p1 = rowptr[row + 1];
  float za = 0.f, zb = 0.f;
  float aa[8], ab[8];
#pragma unroll
  for (int j = 0; j < 8; ++j) { aa[j] = 0.f; ab[j] = 0.f; }
  int p = p0;
  for (; p + 4 <= p1; p += 4) {
    int c0 = col[p], c1 = col[p + 1], c2 = col[p + 2], c3 = col[p + 3];
    float wa0 = ea[c0], wa1 = ea[c1], wa2 = ea[c2], wa3 = ea[c3];
    float wb0 = eb[c0], wb1 = eb[c1], wb2 = eb[c2], wb3 = eb[c3];
    f16x8 va0 = *(const f16x8*)(haf + ((long long)c0 << 6) + (l8 << 3));
    f16x8 va1 = *(const f16x8*)(haf + ((long long)c1 << 6) + (l8 << 3));
    f16x8 va2 = *(const f16x8*)(haf + ((long long)c2 << 6) + (l8 << 3));
    f16x8 va3 = *(const f16x8*)(haf + ((long long)c3 << 6) + (l8 << 3));
    f16x8 vb0 = *(const f16x8*)(hbf + ((long long)c0 << 6) + (l8 << 3));
    f16x8 vb1 = *(const f16x8*)(hbf + ((long long)c1 << 6) + (l8 << 3));
    f16x8 vb2 = *(const f16x8*)(hbf + ((long long)c2 << 6) + (l8 << 3));
    f16x8 vb3 = *(const f16x8*)(hbf + ((long long)c3 << 6) + (l8 << 3));
    za += (wa0 + wa1) + (wa2 + wa3);
    zb += (wb0 + wb1) + (wb2 + wb3);
#pragma unroll
    for (int j = 0; j < 8; ++j) {
      aa[j] += wa0 * (float)va0[j] + wa1 * (float)va1[j] + wa2 * (float)va2[j] + wa3 * (float)va3[j];
      ab[j] += wb0 * (float)vb0[j] + wb1 * (float)vb1[j] + wb2 * (float)vb2[j] + wb3 * (float)vb3[j];
    }
  }
  for (; p < p1; ++p) {
    int c = col[p];
    float wa = ea[c], wb = eb[c];
    f16x8 va = *(const f16x8*)(haf + ((long long)c << 6) + (l8 << 3));
    f16x8 vb = *(const f16x8*)(hbf + ((long long)c << 6) + (l8 << 3));
    za += wa;
    zb += wb;
#pragma unroll
    for (int j = 0; j < 8; ++j) {
      aa[j] += wa * (float)va[j];
      ab[j] += wb * (float)vb[j];
    }
  }
  float ia = za > 0.f ? 1.f / za : 0.f;
  float ib = zb > 0.f ? 1.f / zb : 0.f;
  float pv = pw[0];
  float r[8];
#pragma unroll
  for (int j = 0; j < 8; ++j) {
    float t = aa[j] * ia + ab[j] * ib;
    r[j] = t >= 0.f ? t : pv * t;   // prelu
  }
  if constexpr (sizeof(OutT) == 2) {
    f16x8 o;
#pragma unroll
    for (int j = 0; j < 8; ++j) o[j] = (_Float16)r[j];
    *(f16x8*)((_Float16*)out + (long long)row * 64 + (l8 << 3)) = o;
  } else {
    float* op = (float*)out + (long long)row * 64 + (l8 << 3);
    f32x4 o0 = {r[0], r[1], r[2], r[3]};
    f32x4 o1 = {r[4], r[5], r[6], r[7]};
    *(f32x4*)op = o0;
    *(f32x4*)(op + 4) = o1;
  }
}

// ---------- H2t = H2 @ triW via f16 MFMA ----------
__global__ __launch_bounds__(256) void tri_mfma_kernel(
    const __half* __restrict__ H2, const __half* __restrict__ Wt,
    __half* __restrict__ H2t, int n) {
  const int tid = threadIdx.x;
  const int m0 = blockIdx.x * 64;
  const int wave = tid >> 6;
  const int lane = tid & 63;
  const int quad = lane >> 4;
  const int l16 = lane & 15;
  const int arow = m0 + wave * 16 + l16;
  f32x4 acc[4];
#pragma unroll
  for (int i = 0; i < 4; ++i) acc[i] = (f32x4){0.f, 0.f, 0.f, 0.f};
  const f16x8* Wf = (const f16x8*)Wt;
#pragma unroll
  for (int kc = 0; kc < 2; ++kc) {
    f16x8 af = (f16x8){0, 0, 0, 0, 0, 0, 0, 0};
    if (arow < n) af = *(const f16x8*)((const _Float16*)H2 + (long long)arow * 64 + kc * 32 + quad * 8);
#pragma unroll
    for (int nb = 0; nb < 4; ++nb) {
      f16x8 bf = Wf[(kc * 4 + nb) * 64 + lane];
      acc[nb] = __builtin_amdgcn_mfma_f32_16x16x32_f16(af, bf, acc[nb], 0, 0, 0);
    }
  }
#pragma unroll
  for (int nb = 0; nb < 4; ++nb) {
    int col = nb * 16 + l16;
#pragma unroll
    for (int reg = 0; reg < 4; ++reg) {
      int rg = m0 + wave * 16 + quad * 4 + reg;
      if (rg < n) H2t[(long long)rg * 64 + col] = __float2half(acc[nb][reg]);
    }
  }
}

// ---------- mega edge-row kernel: G = prelu(satL1a + satL1b) + trib + B2 @ H2t ----------
// R6: reverted to R4 structure (sequential head a then head b, 4x unroll each).
// R5's head-interleave REGRESSED (67.5 -> 85.9us): avg degree ~5 means the dual-head
// main loop ran ~once then fell into two divergent tails; +20 VGPR; worse L2 (both
// 25MB tables live at once).  This config measured 67.5us / 3.0 TB/s.
__global__ __launch_bounds__(256) void sat_l1_mega_kernel(
    const int* __restrict__ rp_a, const int* __restrict__ rp_b, const int* __restrict__ rp_B2,
    const int* __restrict__ pool,
    const float* __restrict__ ea, const __half* __restrict__ ha,
    const float* __restrict__ eb, const __half* __restrict__ hb,
    const __half* __restrict__ H2t, const float* __restrict__ trib,
    const float* __restrict__ pw, __half* __restrict__ G, int n) {
  int row = blockIdx.x * 32 + (threadIdx.x >> 3);
  if (row >= n) return;
  int l8 = threadIdx.x & 7;
  const _Float16* haf = (const _Float16*)ha;
  const _Float16* hbf = (const _Float16*)hb;
  const _Float16* h2f = (const _Float16*)H2t;
  float r[8];
  // head a, 4x unrolled
  {
    float za = 0.f, aa[8];
#pragma unroll
    for (int j = 0; j < 8; ++j) aa[j] = 0.f;
    int p0 = rp_a[row], p1 = rp_a[row + 1];
    int p = p0;
    for (; p + 4 <= p1; p += 4) {
      int c0 = pool[p + 0], c1 = pool[p + 1], c2 = pool[p + 2], c3 = pool[p + 3];
      float w0 = ea[c0], w1 = ea[c1], w2 = ea[c2], w3 = ea[c3];
      f16x8 v0 = *(const f16x8*)(haf + ((long long)c0 << 6) + (l8 << 3));
      f16x8 v1 = *(const f16x8*)(haf + ((long long)c1 << 6) + (l8 << 3));
      f16x8 v2 = *(const f16x8*)(haf + ((long long)c2 << 6) + (l8 << 3));
      f16x8 v3 = *(const f16x8*)(haf + ((long long)c3 << 6) + (l8 << 3));
      za += (w0 + w1) + (w2 + w3);
#pragma unroll
      for (int j = 0; j < 8; ++j)
        aa[j] += w0 * (float)v0[j] + w1 * (float)v1[j] + w2 * (float)v2[j] + w3 * (float)v3[j];
    }
    for (; p < p1; ++p) {
      int c = pool[p];
      float w = ea[c];
      f16x8 v = *(const f16x8*)(haf + ((long long)c << 6) + (l8 << 3));
      za += w;
#pragma unroll
      for (int j = 0; j < 8; ++j) aa[j] += w * (float)v[j];
    }
    float iz = za > 0.f ? 1.f / za : 0.f;
#pragma unroll
    for (int j = 0; j < 8; ++j) r[j] = aa[j] * iz;
  }
  // head b, 4x unrolled
  {
    float zb = 0.f, ab[8];
#pragma unroll
    for (int j = 0; j < 8; ++j) ab[j] = 0.f;
    int p0 = rp_b[row], p1 = rp_b[row + 1];
    int p = p0;
    for (; p + 4 <= p1; p += 4) {
      int c0 = pool[p + 0], c1 = pool[p + 1], c2 = pool[p + 2], c3 = pool[p + 3];
      float w0 = eb[c0], w1 = eb[c1], w2 = eb[c2], w3 = eb[c3];
      f16x8 v0 = *(const f16x8*)(hbf + ((long long)c0 << 6) + (l8 << 3));
      f16x8 v1 = *(const f16x8*)(hbf + ((long long)c1 << 6) + (l8 << 3));
      f16x8 v2 = *(const f16x8*)(hbf + ((long long)c2 << 6) + (l8 << 3));
      f16x8 v3 = *(const f16x8*)(hbf + ((long long)c3 << 6) + (l8 << 3));
      zb += (w0 + w1) + (w2 + w3);
#pragma unroll
      for (int j = 0; j < 8; ++j)
        ab[j] += w0 * (float)v0[j] + w1 * (float)v1[j] + w2 * (float)v2[j] + w3 * (float)v3[j];
    }
    for (; p < p1; ++p) {
      int c = pool[p];
      float w = eb[c];
      f16x8 v = *(const f16x8*)(hbf + ((long long)c << 6) + (l8 << 3));
      zb += w;
#pragma unroll
      for (int j = 0; j < 8; ++j) ab[j] += w * (float)v[j];
    }
    float iz = zb > 0.f ? 1.f / zb : 0.f;
#pragma unroll
    for (int j = 0; j < 8; ++j) r[j] += ab[j] * iz;
  }
  float pv = pw[0];
#pragma unroll
  for (int j = 0; j < 8; ++j) r[j] = r[j] >= 0.f ? r[j] : pv * r[j];   // H1 = prelu(...)
  // Tm = B2 @ H2t + trib (avg 1.5 entries/row; 2x unroll)
  float tm[8];
  {
    f32x4 t0 = *(const f32x4*)(trib + (l8 << 3));
    f32x4 t1 = *(const f32x4*)(trib + (l8 << 3) + 4);
#pragma unroll
    for (int j = 0; j < 4; ++j) { tm[j] = t0[j]; tm[j + 4] = t1[j]; }
  }
  {
    int p0 = rp_B2[row], p1 = rp_B2[row + 1];
    int p = p0;
    for (; p + 2 <= p1; p += 2) {
      int e0 = pool[p], e1 = pool[p + 1];
      int c0 = e0 / 3, c1 = e1 / 3;
      float s0 = (e0 - 3 * c0 == 1) ? -1.f : 1.f;
      float s1 = (e1 - 3 * c1 == 1) ? -1.f : 1.f;
      f16x8 v0 = *(const f16x8*)(h2f + ((long long)c0 << 6) + (l8 << 3));
      f16x8 v1 = *(const f16x8*)(h2f + ((long long)c1 << 6) + (l8 << 3));
#pragma unroll
      for (int j = 0; j < 8; ++j) tm[j] += s0 * (float)v0[j] + s1 * (float)v1[j];
    }
    for (; p < p1; ++p) {
      int e = pool[p];
      int c = e / 3;
      float s = (e - 3 * c == 1) ? -1.f : 1.f;
      f16x8 v = *(const f16x8*)(h2f + ((long long)c << 6) + (l8 << 3));
#pragma unroll
      for (int j = 0; j < 8; ++j) tm[j] += s * (float)v[j];
    }
  }
  f16x8 o;
#pragma unroll
  for (int j = 0; j < 8; ++j) o[j] = (_Float16)(r[j] + tm[j]);
  *(f16x8*)((_Float16*)G + (long long)row * 64 + (l8 << 3)) = o;
}

// ---------- out = (H0 + B1 @ G) / 3, 8 lanes per row, B1 loop 8x unrolled ----------
__global__ __launch_bounds__(256) void final_kernel(
    const int* __restrict__ rowptr, const int* __restrict__ ent,
    const float* __restrict__ H0, const __half* __restrict__ G,
    float* __restrict__ out, int n) {
  int row = blockIdx.x * 32 + (threadIdx.x >> 3);
  if (row >= n) return;
  int l8 = threadIdx.x & 7;
  const _Float16* gf = (const _Float16*)G;
  float acc[8];
  {
    const float* hp = H0 + (long long)row * 64 + (l8 << 3);
    f32x4 a0 = *(const f32x4*)hp;
    f32x4 a1 = *(const f32x4*)(hp + 4);
#pragma unroll
    for (int j = 0; j < 4; ++j) { acc[j] = a0[j]; acc[j + 4] = a1[j]; }
  }
  int p0 = rowptr[row], p1 = rowptr[row + 1];
  int p = p0;
  for (; p + 8 <= p1; p += 8) {
    int e[8];
#pragma unroll
    for (int k = 0; k < 8; ++k) e[k] = ent[p + k];
    f16x8 v[8];
#pragma unroll
    for (int k = 0; k < 8; ++k)
      v[k] = *(const f16x8*)(gf + ((long long)(e[k] >> 1) << 6) + (l8 << 3));
#pragma unroll
    for (int k = 0; k < 8; ++k) {
      float s = (e[k] & 1) ? -1.f : 1.f;
#pragma unroll
      for (int j = 0; j < 8; ++j) acc[j] += s * (float)v[k][j];
    }
  }
  for (; p + 4 <= p1; p += 4) {
    int e0 = ent[p], e1 = ent[p + 1], e2 = ent[p + 2], e3 = ent[p + 3];
    float s0 = (e0 & 1) ? -1.f : 1.f;
    float s1 = (e1 & 1) ? -1.f : 1.f;
    float s2 = (e2 & 1) ? -1.f : 1.f;
    float s3 = (e3 & 1) ? -1.f : 1.f;
    f16x8 v0 = *(const f16x8*)(gf + ((long long)(e0 >> 1) << 6) + (l8 << 3));
    f16x8 v1 = *(const f16x8*)(gf + ((long long)(e1 >> 1) << 6) + (l8 << 3));
    f16x8 v2 = *(const f16x8*)(gf + ((long long)(e2 >> 1) << 6) + (l8 << 3));
    f16x8 v3 = *(const f16x8*)(gf + ((long long)(e3 >> 1) << 6) + (l8 << 3));
#pragma unroll
    for (int j = 0; j < 8; ++j)
      acc[j] += s0 * (float)v0[j] + s1 * (float)v1[j] + s2 * (float)v2[j] + s3 * (float)v3[j];
  }
  for (; p < p1; ++p) {
    int e = ent[p];
    float s = (e & 1) ? -1.f : 1.f;
    f16x8 v = *(const f16x8*)(gf + ((long long)(e >> 1) << 6) + (l8 << 3));
#pragma unroll
    for (int j = 0; j < 8; ++j) acc[j] += s * (float)v[j];
  }
  float* op = out + (long long)row * 64 + (l8 << 3);
  f32x4 o0 = {acc[0] * (1.0f / 3.0f), acc[1] * (1.0f / 3.0f), acc[2] * (1.0f / 3.0f), acc[3] * (1.0f / 3.0f)};
  f32x4 o1 = {acc[4] * (1.0f / 3.0f), acc[5] * (1.0f / 3.0f), acc[6] * (1.0f / 3.0f), acc[7] * (1.0f / 3.0f)};
  *(f32x4*)op = o0;
  *(f32x4*)(op + 4) = o1;
}

extern "C" void kernel_launch(void* const* d_in, const int* in_sizes, int n_in,
                              void* d_out, int out_size, void* d_ws, size_t ws_size,
                              hipStream_t stream) {
  const float* X0 = (const float*)d_in[0];
  const int* E1 = (const int*)d_in[1];
  const int* T2 = (const int*)d_in[2];
  const int* L0i = (const int*)d_in[3];
  const int* L1ai = (const int*)d_in[4];
  const int* L1bi = (const int*)d_in[5];
  const int* L2i = (const int*)d_in[6];
  const int* B1i = (const int*)d_in[7];
  const int* B2i = (const int*)d_in[9];
  const float* W = (const float*)d_in[11];
  const float* bvec = (const float*)d_in[12];
  // a1_w/a1_b are mathematically dead: s1[r] cancels in the row softmax.
  const float* a2w = (const float*)d_in[15];
  const float* a2b = (const float*)d_in[16];
  const float* pw = (const float*)d_in[17];
  const float* triW = (const float*)d_in[18];
  const float* trib = (const float*)d_in[19];
  float* out = (float*)d_out;

  char* base = (char*)d_ws;
  size_t off = 0;
  auto alloc = [&](size_t bytes) -> void* {
    void* p = base + off;
    off += (bytes + 255) & ~(size_t)255;
    return p;
  };
  unsigned int* Xbit = (unsigned int*)alloc((size_t)N0 * 16 * 4);
  unsigned short* Bp = (unsigned short*)alloc((size_t)3 * 65536 * 2);
  __half* Wt = (__half*)alloc((size_t)4096 * 2);
  __half* h0 = (__half*)alloc((size_t)N0 * 64 * 2);
  __half* h1 = (__half*)alloc((size_t)N0 * 64 * 2);
  __half* h2 = (__half*)alloc((size_t)N1 * 64 * 2);
  __half* h3 = (__half*)alloc((size_t)N1 * 64 * 2);
  __half* h4 = (__half*)alloc((size_t)N2 * 64 * 2);
  __half* h5 = (__half*)alloc((size_t)N2 * 64 * 2);
  float* e0 = (float*)alloc((size_t)N0 * 4);
  float* e1 = (float*)alloc((size_t)N0 * 4);
  float* e2 = (float*)alloc((size_t)N1 * 4);
  float* e3 = (float*)alloc((size_t)N1 * 4);
  float* e4 = (float*)alloc((size_t)N2 * 4);
  float* e5 = (float*)alloc((size_t)N2 * 4);
  float* H0 = (float*)alloc((size_t)N0 * 64 * 4);
  __half* H2 = (__half*)alloc((size_t)N2 * 64 * 2);
  __half* H2t = (__half*)alloc((size_t)N2 * 64 * 2);
  __half* G = (__half*)alloc((size_t)N1 * 64 * 2);
  int* gscan = (int*)alloc((size_t)(CNT_TOT + 1) * 4);
  int* pool = (int*)alloc((size_t)TOT_E * 4);
  int* stage = (int*)alloc((size_t)TOT_E * 4);
  int* bh = (int*)alloc((size_t)BH_N * 4);
  int* bhoff = (int*)alloc((size_t)(BH_N + 1) * 4);
  int* bsum = (int*)alloc((size_t)(BH_SCAN_BLOCKS + 1) * 4);

  pack_bits_kernel<<<(N0 + 3) / 4, 256, 0, stream>>>(X0, Xbit);
  pack_w_kernel<<<(3 * 65536 + 255) / 256, 256, 0, stream>>>(W, Bp);
  pack_wt_kernel<<<16, 256, 0, stream>>>(triW, Wt);

  gemm_sat_kernel<1><<<(N0 + 127) / 128, 256, 0, stream>>>(Xbit, nullptr, Bp, bvec, a2w, a2b, 0, N0, h0, h1, e0, e1);
  gemm_sat_kernel<2><<<(N1 + 127) / 128, 256, 0, stream>>>(Xbit, E1, Bp + 65536, bvec, a2w, a2b, 2, N1, h2, h3, e2, e3);
  gemm_sat_kernel<3><<<(N2 + 127) / 128, 256, 0, stream>>>(Xbit, T2, Bp + 2 * 65536, bvec, a2w, a2b, 4, N2, h4, h5, e4, e5);

  // radix-partition CSR build (no row-level global histogram needed)
  blkhist_kernel<<<NBLK, 256, 0, stream>>>(L0i, L1ai, L1bi, L2i, B1i, B2i, bh);
  scan_partial_kernel<<<BH_SCAN_BLOCKS, 256, 0, stream>>>(bh, bsum, BH_N);
  scan_bsum_kernel<<<1, 256, 0, stream>>>(bsum, BH_SCAN_BLOCKS);
  scan_write_kernel<<<BH_SCAN_BLOCKS, 256, 0, stream>>>(bh, bsum, bhoff, BH_N, BH_SCAN_BLOCKS);
  stage_part_kernel<<<NBLK, 256, 0, stream>>>(L0i, L1ai, L1bi, L2i, B1i, B2i, bhoff, stage);
  fill_cb_kernel<<<CB, 256, 0, stream>>>(bhoff, stage, gscan, pool);

  const int* rp0 = gscan + SEG_L0;
  const int* rp1a = gscan + SEG_L1A;
  const int* rp1b = gscan + SEG_L1B;
  const int* rp2 = gscan + SEG_L2;
  const int* rpB1 = gscan + SEG_B1;
  const int* rpB2 = gscan + SEG_B2;

  sat_dual_z_kernel<float><<<(N0 + 31) / 32, 256, 0, stream>>>(rp0, pool, e0, h0, e1, h1, pw, H0, N0);
  sat_dual_z_kernel<__half><<<(N2 + 31) / 32, 256, 0, stream>>>(rp2, pool, e4, h4, e5, h5, pw, H2, N2);
  tri_mfma_kernel<<<(N2 + 63) / 64, 256, 0, stream>>>(H2, Wt, H2t, N2);
  sat_l1_mega_kernel<<<(N1 + 31) / 32, 256, 0, stream>>>(rp1a, rp1b, rpB2, pool, e2, h2, e3, h3,
                                                         H2t, trib, pw, G, N1);
  final_kernel<<<(N0 + 31) / 32, 256, 0, stream>>>(rpB1, pool, H0, G, out, N0);
}

// Round 7
// 550.664 us; speedup vs baseline: 1.0527x; 1.0199x over previous
//
#include <hip/hip_runtime.h>
#include <hip/hip_fp16.h>

static constexpr int N0 = 50000;
static constexpr int N1 = 200000;
static constexpr int N2 = 100000;
static constexpr int NNZ0 = 600000;
static constexpr int NNZ1 = 1000000;
static constexpr int NNZ2 = 600000;
static constexpr int FIN = 500;

// concatenated count layout: [L0 | L1a | L1b | L2 | B1 | B2]
static constexpr int SEG_L0 = 0;
static constexpr int SEG_L1A = 50000;
static constexpr int SEG_L1B = 250000;
static constexpr int SEG_L2 = 450000;
static constexpr int SEG_B1 = 550000;
static constexpr int SEG_B2 = 600000;
static constexpr int CNT_TOT = 800000;
static constexpr int TOT_E = NNZ0 + NNZ1 + NNZ1 + NNZ2 + 2 * N1 + 3 * N2;  // 3.9M
// radix partition: 512 partition blocks x 1563 coarse buckets (512 rows each).
static constexpr int NBLK = 512;
static constexpr int EPB = (TOT_E + NBLK - 1) / NBLK;        // 7618 entries/block
static constexpr int CB_SHIFT = 9;                           // 512 rows per coarse bucket
static constexpr int CB = (CNT_TOT + (1 << CB_SHIFT) - 1) >> CB_SHIFT;  // 1563
static constexpr int BH_N = CB * NBLK;                       // 800256
static constexpr int SCAN_CHUNK = 4096;
static constexpr int BH_SCAN_BLOCKS = (BH_N + SCAN_CHUNK - 1) / SCAN_CHUNK;  // 196 (<=256 cap)

typedef __attribute__((ext_vector_type(8))) short bf16x8;
typedef __attribute__((ext_vector_type(8))) _Float16 f16x8;
typedef __attribute__((ext_vector_type(4))) float f32x4;

typedef const unsigned int __attribute__((address_space(1)))* gas_u32p;
typedef unsigned int __attribute__((address_space(3)))* las_u32p;

__device__ __forceinline__ unsigned short f2bf(float f) {
  unsigned int b = __float_as_uint(f);
  b = (b + 0x7FFFu + ((b >> 16) & 1u)) >> 16;   // RNE
  return (unsigned short)b;
}

// ---------- pack X0 -> binary bitmasks: 512 bits = 16 uints per row (3.2 MB, L2-resident) ----------
__global__ __launch_bounds__(256) void pack_bits_kernel(const float* __restrict__ X0,
                                                        unsigned int* __restrict__ Xbit) {
  int row = blockIdx.x * 4 + (threadIdx.x >> 6);
  if (row >= N0) return;
  int lane = threadIdx.x & 63;
  const float* xr = X0 + (long long)row * FIN;
#pragma unroll
  for (int i = 0; i < 8; ++i) {
    int c = i * 64 + lane;
    bool pred = (c < FIN) && (xr[c] != 0.0f);
    unsigned long long m = __ballot(pred);
    if (lane == 0) {
      Xbit[row * 16 + 2 * i] = (unsigned int)m;
      Xbit[row * 16 + 2 * i + 1] = (unsigned int)(m >> 32);
    }
  }
}

// ---------- pack W -> bf16 MFMA B-fragment layout: [level][kc][nb][lane][j] ----------
__global__ void pack_w_kernel(const float* __restrict__ W, unsigned short* __restrict__ Bp) {
  int g = blockIdx.x * 256 + threadIdx.x;
  if (g >= 3 * 65536) return;
  int j = g & 7;
  int lane = (g >> 3) & 63;
  int nb = (g >> 9) & 7;
  int kc = (g >> 12) & 15;
  int level = g >> 16;
  int k = kc * 32 + (lane >> 4) * 8 + j;
  int col128 = nb * 16 + (lane & 15);
  int head = level * 2 + (col128 >> 6);
  int col = col128 & 63;
  float f = 0.0f;
  if (k < FIN) f = W[((long long)head * FIN + k) * 64 + col];
  Bp[g] = f2bf(f);
}

// ---------- pack triW -> f16 B-fragment layout: [kc(2)][nb(4)][lane][j] ----------
__global__ void pack_wt_kernel(const float* __restrict__ triW, __half* __restrict__ Wt) {
  int g = blockIdx.x * 256 + threadIdx.x;
  if (g >= 4096) return;
  int j = g & 7;
  int lane = (g >> 3) & 63;
  int nb = (g >> 9) & 3;
  int kc = g >> 11;
  int k = kc * 32 + (lane >> 4) * 8 + j;
  int col = nb * 16 + (lane & 15);
  Wt[g] = __float2half(triW[k * 64 + col]);
}

// ---------- fused bit-gather(AND) + in-register bf16 expansion + MFMA ----------
// R7: 3-buffer rotating LDS stage, 2-deep prefetch, counted vmcnt(2) (never drain
// to 0 in steady state) -- the R3/R6 single-deep version waited vmcnt(0) each kc,
// exposing (stage latency - one compute phase) at all 16 barriers.
template <int NSRC>
__global__ __launch_bounds__(256, 4) void gemm_sat_kernel(
    const unsigned int* __restrict__ Xbit, const int* __restrict__ srcidx,
    const unsigned short* __restrict__ Bp, const float* __restrict__ bvec,
    const float* __restrict__ a2w, const float* __restrict__ a2b, int head_lo,
    int M, __half* __restrict__ h_lo, __half* __restrict__ h_hi,
    float* __restrict__ e_lo, float* __restrict__ e_hi) {
  __shared__ __align__(16) unsigned int Sb[128 * 20];
  __shared__ __align__(16) unsigned short Bs[3][4096];   // 3 x 8KB rotating buffers
  const int tid = threadIdx.x;
  const int m0 = blockIdx.x * 128;
  const int wave = tid >> 6;
  const int lane = tid & 63;
  {
    // 2 threads per row: thread handles uint4 chunks {2*hf, 2*hf+1} of the 64B row mask
    int rg = m0 + (tid >> 1);
    int hf = tid & 1;
    uint4 a[2];
#pragma unroll
    for (int c2 = 0; c2 < 2; ++c2) a[c2] = make_uint4(0u, 0u, 0u, 0u);
    if (rg < M) {
      if (NSRC == 1) {
        const uint4* up = (const uint4*)(Xbit + (long long)rg * 16);
#pragma unroll
        for (int c2 = 0; c2 < 2; ++c2) a[c2] = up[hf * 2 + c2];
      } else if (NSRC == 2) {
        const uint4* up = (const uint4*)(Xbit + (long long)srcidx[2 * rg + 0] * 16);
        const uint4* vp = (const uint4*)(Xbit + (long long)srcidx[2 * rg + 1] * 16);
#pragma unroll
        for (int c2 = 0; c2 < 2; ++c2) {
          uint4 u = up[hf * 2 + c2], v = vp[hf * 2 + c2];
          a[c2] = make_uint4(u.x & v.x, u.y & v.y, u.z & v.z, u.w & v.w);
        }
      } else {
        const uint4* up = (const uint4*)(Xbit + (long long)srcidx[3 * rg + 0] * 16);
        const uint4* vp = (const uint4*)(Xbit + (long long)srcidx[3 * rg + 1] * 16);
        const uint4* wp = (const uint4*)(Xbit + (long long)srcidx[3 * rg + 2] * 16);
#pragma unroll
        for (int c2 = 0; c2 < 2; ++c2) {
          uint4 u = up[hf * 2 + c2], v = vp[hf * 2 + c2], w = wp[hf * 2 + c2];
          a[c2] = make_uint4(u.x & v.x & w.x, u.y & v.y & w.y, u.z & v.z & w.z, u.w & v.w & w.w);
        }
      }
    }
#pragma unroll
    for (int c2 = 0; c2 < 2; ++c2)
      *(uint4*)(Sb + (tid >> 1) * 20 + (hf * 2 + c2) * 4) = a[c2];
  }

  // stage B slab for kc (8KB = 4 waves x 2 instrs x 1KB) direct to LDS, no VGPR round-trip.
  auto stageB = [&](int buf, int kc2) {
    int chunk0 = wave * 2;
    const unsigned short* g0 = Bp + kc2 * 4096 + chunk0 * 512 + lane * 8;
    __builtin_amdgcn_global_load_lds((gas_u32p)(const void*)g0,
                                     (las_u32p)(void*)&Bs[buf][chunk0 * 512], 16, 0, 0);
    __builtin_amdgcn_global_load_lds((gas_u32p)(const void*)(g0 + 512),
                                     (las_u32p)(void*)&Bs[buf][chunk0 * 512 + 512], 16, 0, 0);
  };
  stageB(0, 0);
  stageB(1, 1);
  __syncthreads();   // one-time full drain: Sb writes + both prologue stages complete

  const int quad = lane >> 4;
  const int l16 = lane & 15;
  f32x4 acc[8][2];   // [nb][sub]
#pragma unroll
  for (int i = 0; i < 8; ++i)
#pragma unroll
    for (int s = 0; s < 2; ++s) acc[i][s] = (f32x4){0.f, 0.f, 0.f, 0.f};

  for (int kc = 0; kc < 16; ++kc) {
    const int cur = kc % 3;
    if (kc + 2 < 16) stageB((kc + 2) % 3, kc + 2);   // 2-deep prefetch, overlaps 2 compute phases
    bf16x8 af[2];
#pragma unroll
    for (int sub = 0; sub < 2; ++sub) {
      unsigned int bw = Sb[(wave * 32 + sub * 16 + l16) * 20 + kc];
      unsigned int byte = (bw >> (quad * 8)) & 0xFFu;
#pragma unroll
      for (int j = 0; j < 4; ++j) {
        unsigned int b2 = (byte >> (2 * j)) & 3u;
        ((unsigned int*)&af[sub])[j] = ((b2 & 1u) | ((b2 & 2u) << 15)) * 0x3F80u;
      }
    }
#pragma unroll
    for (int nb = 0; nb < 8; ++nb) {
      bf16x8 bf = *(const bf16x8*)&Bs[cur][(nb * 64 + lane) * 8];
#pragma unroll
      for (int sub = 0; sub < 2; ++sub)
        acc[nb][sub] = __builtin_amdgcn_mfma_f32_16x16x32_bf16(af[sub], bf, acc[nb][sub], 0, 0, 0);
    }
    if (kc < 15) {
      // counted wait: only the NEXT buffer's stage (issued last kc) must have landed;
      // the stage issued THIS kc (2 loads) stays in flight across the barrier.
      if (kc + 2 < 16) asm volatile("s_waitcnt vmcnt(2)" ::: "memory");
      else             asm volatile("s_waitcnt vmcnt(0)" ::: "memory");
      __builtin_amdgcn_sched_barrier(0);
      __builtin_amdgcn_s_barrier();                       // raw barrier: no lgkm/vm drain churn
    }
  }

  float bia[8], aw[8];
#pragma unroll
  for (int nb = 0; nb < 8; ++nb) {
    int col128 = nb * 16 + l16;
    int hh = col128 >> 6, col = col128 & 63;
    bia[nb] = bvec[(head_lo + hh) * 64 + col];
    aw[nb] = a2w[(head_lo + hh) * 64 + col];
  }
  float blo = a2b[head_lo], bhi = a2b[head_lo + 1];
#pragma unroll
  for (int sub = 0; sub < 2; ++sub) {
    float plo[4] = {0.f, 0.f, 0.f, 0.f};
    float phi[4] = {0.f, 0.f, 0.f, 0.f};
#pragma unroll
    for (int nb = 0; nb < 8; ++nb) {
      int col128 = nb * 16 + l16;
      int hh = col128 >> 6, col = col128 & 63;
      __half* hdst = hh ? h_hi : h_lo;
#pragma unroll
      for (int reg = 0; reg < 4; ++reg) {
        int rg = m0 + wave * 32 + sub * 16 + quad * 4 + reg;   // C/D: row=quad*4+reg, col=l16
        float v = acc[nb][sub][reg] + bia[nb];
        if (rg < M) hdst[(long long)rg * 64 + col] = __float2half(v);
        if (hh) phi[reg] += v * aw[nb]; else plo[reg] += v * aw[nb];
      }
    }
#pragma unroll
    for (int off = 1; off < 16; off <<= 1) {
#pragma unroll
      for (int reg = 0; reg < 4; ++reg) {
        plo[reg] += __shfl_xor(plo[reg], off);
        phi[reg] += __shfl_xor(phi[reg], off);
      }
    }
    if (l16 == 0) {
#pragma unroll
      for (int reg = 0; reg < 4; ++reg) {
        int rg = m0 + wave * 32 + sub * 16 + quad * 4 + reg;
        if (rg < M) {
          e_lo[rg] = __expf(plo[reg] + blo);   // |s2| small by construction: no max needed
          e_hi[rg] = __expf(phi[reg] + bhi);
        }
      }
    }
  }
}

// ---------- entry decode shared by partition passes ----------
template <bool NEED_VAL>
__device__ __forceinline__ void decode_entry(
    int g, const int* __restrict__ r0, const int* __restrict__ r1a,
    const int* __restrict__ r1b, const int* __restrict__ r2,
    const int* __restrict__ rb1, const int* __restrict__ rb2, int& row, int& val) {
  if (g < 600000) { int l = g; row = SEG_L0 + r0[l]; if (NEED_VAL) val = r0[NNZ0 + l]; }
  else if (g < 1600000) { int l = g - 600000; row = SEG_L1A + r1a[l]; if (NEED_VAL) val = r1a[NNZ1 + l]; }
  else if (g < 2600000) { int l = g - 1600000; row = SEG_L1B + r1b[l]; if (NEED_VAL) val = r1b[NNZ1 + l]; }
  else if (g < 3200000) { int l = g - 2600000; row = SEG_L2 + r2[l]; if (NEED_VAL) val = r2[NNZ2 + l]; }
  else if (g < 3600000) { int l = g - 3200000; row = SEG_B1 + rb1[l]; val = l; }   // B1: entry id
  else { int l = g - 3600000; row = SEG_B2 + rb2[l]; val = l; }                    // B2: entry id
}

// ---------- pass 1: per-(block, coarse-bucket) histogram via LDS, 4x-unrolled MLP ----------
__global__ __launch_bounds__(256) void blkhist_kernel(
    const int* __restrict__ r0, const int* __restrict__ r1a, const int* __restrict__ r1b,
    const int* __restrict__ r2, const int* __restrict__ rb1, const int* __restrict__ rb2,
    int* __restrict__ bh) {
  __shared__ int hcnt[CB];
  int blk = blockIdx.x;
  for (int i = threadIdx.x; i < CB; i += 256) hcnt[i] = 0;
  __syncthreads();
  int g0 = blk * EPB;
  int g1 = g0 + EPB; if (g1 > TOT_E) g1 = TOT_E;
  int g = g0 + threadIdx.x;
  for (; g + 768 < g1; g += 1024) {
    int ra, rb, rc, rd, v;
    decode_entry<false>(g, r0, r1a, r1b, r2, rb1, rb2, ra, v);
    decode_entry<false>(g + 256, r0, r1a, r1b, r2, rb1, rb2, rb, v);
    decode_entry<false>(g + 512, r0, r1a, r1b, r2, rb1, rb2, rc, v);
    decode_entry<false>(g + 768, r0, r1a, r1b, r2, rb1, rb2, rd, v);
    atomicAdd(&hcnt[ra >> CB_SHIFT], 1);
    atomicAdd(&hcnt[rb >> CB_SHIFT], 1);
    atomicAdd(&hcnt[rc >> CB_SHIFT], 1);
    atomicAdd(&hcnt[rd >> CB_SHIFT], 1);
  }
  for (; g < g1; g += 256) {
    int row, val;
    decode_entry<false>(g, r0, r1a, r1b, r2, rb1, rb2, row, val);
    atomicAdd(&hcnt[row >> CB_SHIFT], 1);
  }
  __syncthreads();
  for (int i = threadIdx.x; i < CB; i += 256) bh[i * NBLK + blk] = hcnt[i];
}

// ---------- 3-phase scan (parameterized size) ----------
__global__ __launch_bounds__(256) void scan_partial_kernel(const int* __restrict__ cnt,
                                                           int* __restrict__ bsum, int n) {
  __shared__ int s[256];
  int b = blockIdx.x, t = threadIdx.x;
  int base = b * SCAN_CHUNK + t * 16;
  int sum = 0;
#pragma unroll
  for (int i = 0; i < 16; ++i) {
    int idx = base + i;
    if (idx < n) sum += cnt[idx];
  }
  s[t] = sum;
  __syncthreads();
  for (int off = 128; off > 0; off >>= 1) {
    if (t < off) s[t] += s[t + off];
    __syncthreads();
  }
  if (t == 0) bsum[b] = s[0];
}

__global__ __launch_bounds__(256) void scan_bsum_kernel(int* __restrict__ bsum, int nb) {
  __shared__ int s[256];
  int t = threadIdx.x;
  int v = (t < nb) ? bsum[t] : 0;
  s[t] = v;
  __syncthreads();
  for (int off = 1; off < 256; off <<= 1) {
    int u = (t >= off) ? s[t - off] : 0;
    __syncthreads();
    s[t] += u;
    __syncthreads();
  }
  if (t < nb) bsum[t] = (t == 0) ? 0 : s[t - 1];
  if (t == 0) bsum[nb] = s[nb - 1];
}

__global__ __launch_bounds__(256) void scan_write_kernel(const int* __restrict__ cnt,
                                                         const int* __restrict__ bsum,
                                                         int* __restrict__ gout, int n, int nb) {
  __shared__ int s[256];
  int b = blockIdx.x, t = threadIdx.x;
  int base = b * SCAN_CHUNK + t * 16;
  int loc[16];
  int sum = 0;
#pragma unroll
  for (int i = 0; i < 16; ++i) {
    int idx = base + i;
    int v = (idx < n) ? cnt[idx] : 0;
    loc[i] = sum;
    sum += v;
  }
  s[t] = sum;
  __syncthreads();
  for (int off = 1; off < 256; off <<= 1) {
    int u = (t >= off) ? s[t - off] : 0;
    __syncthreads();
    s[t] += u;
    __syncthreads();
  }
  int toff = bsum[b] + ((t == 0) ? 0 : s[t - 1]);
#pragma unroll
  for (int i = 0; i < 16; ++i) {
    int idx = base + i;
    if (idx < n) gout[idx] = toff + loc[i];
  }
  if (b == 0 && t == 0) gout[n] = bsum[nb];
}

// ---------- pass 2: write packed (row_lo,val) into block-PRIVATE per-bucket runs, 4x MLP ----------
// stage entry packed to 4B -- within a bucket only row&511 (9b) + val (<=20b) needed.
__global__ __launch_bounds__(256) void stage_part_kernel(
    const int* __restrict__ r0, const int* __restrict__ r1a, const int* __restrict__ r1b,
    const int* __restrict__ r2, const int* __restrict__ rb1, const int* __restrict__ rb2,
    const int* __restrict__ bhoff, int* __restrict__ stage) {
  __shared__ int lcur[CB];
  int blk = blockIdx.x;
  for (int i = threadIdx.x; i < CB; i += 256) lcur[i] = bhoff[i * NBLK + blk];
  __syncthreads();
  int g0 = blk * EPB;
  int g1 = g0 + EPB; if (g1 > TOT_E) g1 = TOT_E;
  const int rmask = (1 << CB_SHIFT) - 1;
  int g = g0 + threadIdx.x;
  for (; g + 768 < g1; g += 1024) {
    int ra, rb, rc, rd, va, vb, vc, vd;
    decode_entry<true>(g, r0, r1a, r1b, r2, rb1, rb2, ra, va);
    decode_entry<true>(g + 256, r0, r1a, r1b, r2, rb1, rb2, rb, vb);
    decode_entry<true>(g + 512, r0, r1a, r1b, r2, rb1, rb2, rc, vc);
    decode_entry<true>(g + 768, r0, r1a, r1b, r2, rb1, rb2, rd, vd);
    int pa = atomicAdd(&lcur[ra >> CB_SHIFT], 1);
    int pb = atomicAdd(&lcur[rb >> CB_SHIFT], 1);
    int pc = atomicAdd(&lcur[rc >> CB_SHIFT], 1);
    int pd = atomicAdd(&lcur[rd >> CB_SHIFT], 1);
    stage[pa] = ((ra & rmask) << 20) | va;
    stage[pb] = ((rb & rmask) << 20) | vb;
    stage[pc] = ((rc & rmask) << 20) | vc;
    stage[pd] = ((rd & rmask) << 20) | vd;
  }
  for (; g < g1; g += 256) {
    int row, val;
    decode_entry<true>(g, r0, r1a, r1b, r2, rb1, rb2, row, val);
    int pos = atomicAdd(&lcur[row >> CB_SHIFT], 1);   // run is block-private
    stage[pos] = ((row & rmask) << 20) | val;
  }
}

// ---------- pass 3: per coarse-bucket: derive gscan locally + scatter pool slice ----------
// 1563 blocks x 512-row buckets, 4x-unrolled MLP, 4B packed stage entries.
__global__ __launch_bounds__(256) void fill_cb_kernel(
    const int* __restrict__ bhoff, const int* __restrict__ stage,
    int* __restrict__ gscan, int* __restrict__ pool) {
  __shared__ int hist[1 << CB_SHIFT];   // 512 row counters -> offsets -> cursors
  __shared__ int sums[256];
  const int cb = blockIdx.x;
  const int t = threadIdx.x;
  const int base_row = cb << CB_SHIFT;
  int nrows = CNT_TOT - base_row;
  if (nrows > (1 << CB_SHIFT)) nrows = 1 << CB_SHIFT;
  const int s0 = bhoff[cb * NBLK];
  const int s1 = bhoff[(cb + 1) * NBLK];   // bhoff[BH_N] = TOT_E covers cb == CB-1
  for (int i = t; i < (1 << CB_SHIFT); i += 256) hist[i] = 0;
  __syncthreads();
  {
    int i = s0 + t;
    for (; i + 768 < s1; i += 1024) {
      int ra = stage[i] >> 20, rb = stage[i + 256] >> 20,
          rc = stage[i + 512] >> 20, rd = stage[i + 768] >> 20;
      atomicAdd(&hist[ra], 1);
      atomicAdd(&hist[rb], 1);
      atomicAdd(&hist[rc], 1);
      atomicAdd(&hist[rd], 1);
    }
    for (; i < s1; i += 256) atomicAdd(&hist[stage[i] >> 20], 1);
  }
  __syncthreads();
  // exclusive scan of the 512 counts; thread t owns slots [2t, 2t+2)
  int loc[2];
  int sum = 0;
#pragma unroll
  for (int j = 0; j < 2; ++j) { loc[j] = sum; sum += hist[t * 2 + j]; }
  sums[t] = sum;
  __syncthreads();
  for (int off = 1; off < 256; off <<= 1) {
    int u = (t >= off) ? sums[t - off] : 0;
    __syncthreads();
    sums[t] += u;
    __syncthreads();
  }
  int pre = (t == 0) ? 0 : sums[t - 1];
#pragma unroll
  for (int j = 0; j < 2; ++j) hist[t * 2 + j] = s0 + pre + loc[j];   // row start offsets
  __syncthreads();
  for (int i = t; i < nrows; i += 256) gscan[base_row + i] = hist[i];
  if (cb == CB - 1 && t == 0) gscan[CNT_TOT] = TOT_E;
  __syncthreads();
  {
    int i = s0 + t;
    for (; i + 768 < s1; i += 1024) {
      int a = stage[i], b = stage[i + 256], c = stage[i + 512], d = stage[i + 768];
      int pa = atomicAdd(&hist[a >> 20], 1);
      int pb = atomicAdd(&hist[b >> 20], 1);
      int pc = atomicAdd(&hist[c >> 20], 1);
      int pd = atomicAdd(&hist[d >> 20], 1);
      pool[pa] = a & 0xFFFFF;
      pool[pb] = b & 0xFFFFF;
      pool[pc] = c & 0xFFFFF;
      pool[pd] = d & 0xFFFFF;
    }
    for (; i < s1; i += 256) {
      int rv = stage[i];
      int pos = atomicAdd(&hist[rv >> 20], 1);
      pool[pos] = rv & 0xFFFFF;   // slice is block-private: stays in one L2, written once
    }
  }
}

// ---------- SAT dual (L2 only now): 8 lanes per row, 4x-unrolled dual-table gather ----------
__global__ __launch_bounds__(256) void sat_dual_z_kernel(
    const int* __restrict__ rowptr, const int* __restrict__ col,
    const float* __restrict__ ea, const __half* __restrict__ ha,
    const float* __restrict__ eb, const __half* __restrict__ hb,
    const float* __restrict__ pw, __half* __restrict__ out, int n) {
  int row = blockIdx.x * 32 + (threadIdx.x >> 3);
  if (row >= n) return;
  int l8 = threadIdx.x & 7;
  const _Float16* haf = (const _Float16*)ha;
  const _Float16* hbf = (const _Float16*)hb;
  int p0 = rowptr[row], p1 = rowptr[row + 1];
  float za = 0.f, zb = 0.f;
  float aa[8], ab[8];
#pragma unroll
  for (int j = 0; j < 8; ++j) { aa[j] = 0.f; ab[j] = 0.f; }
  int p = p0;
  for (; p + 4 <= p1; p += 4) {
    int c0 = col[p], c1 = col[p + 1], c2 = col[p + 2], c3 = col[p + 3];
    float wa0 = ea[c0], wa1 = ea[c1], wa2 = ea[c2], wa3 = ea[c3];
    float wb0 = eb[c0], wb1 = eb[c1], wb2 = eb[c2], wb3 = eb[c3];
    f16x8 va0 = *(const f16x8*)(haf + ((long long)c0 << 6) + (l8 << 3));
    f16x8 va1 = *(const f16x8*)(haf + ((long long)c1 << 6) + (l8 << 3));
    f16x8 va2 = *(const f16x8*)(haf + ((long long)c2 << 6) + (l8 << 3));
    f16x8 va3 = *(const f16x8*)(haf + ((long long)c3 << 6) + (l8 << 3));
    f16x8 vb0 = *(const f16x8*)(hbf + ((long long)c0 << 6) + (l8 << 3));
    f16x8 vb1 = *(const f16x8*)(hbf + ((long long)c1 << 6) + (l8 << 3));
    f16x8 vb2 = *(const f16x8*)(hbf + ((long long)c2 << 6) + (l8 << 3));
    f16x8 vb3 = *(const f16x8*)(hbf + ((long long)c3 << 6) + (l8 << 3));
    za += (wa0 + wa1) + (wa2 + wa3);
    zb += (wb0 + wb1) + (wb2 + wb3);
#pragma unroll
    for (int j = 0; j < 8; ++j) {
      aa[j] += wa0 * (float)va0[j] + wa1 * (float)va1[j] + wa2 * (float)va2[j] + wa3 * (float)va3[j];
      ab[j] += wb0 * (float)vb0[j] + wb1 * (float)vb1[j] + wb2 * (float)vb2[j] + wb3 * (float)vb3[j];
    }
  }
  for (; p < p1; ++p) {
    int c = col[p];
    float wa = ea[c], wb = eb[c];
    f16x8 va = *(const f16x8*)(haf + ((long long)c << 6) + (l8 << 3));
    f16x8 vb = *(const f16x8*)(hbf + ((long long)c << 6) + (l8 << 3));
    za += wa;
    zb += wb;
#pragma unroll
    for (int j = 0; j < 8; ++j) {
      aa[j] += wa * (float)va[j];
      ab[j] += wb * (float)vb[j];
    }
  }
  float ia = za > 0.f ? 1.f / za : 0.f;
  float ib = zb > 0.f ? 1.f / zb : 0.f;
  float pv = pw[0];
  f16x8 o;
#pragma unroll
  for (int j = 0; j < 8; ++j) {
    float t = aa[j] * ia + ab[j] * ib;
    t = t >= 0.f ? t : pv * t;   // prelu
    o[j] = (_Float16)t;
  }
  *(f16x8*)((_Float16*)out + (long long)row * 64 + (l8 << 3)) = o;
}

// ---------- H2t = H2 @ triW via f16 MFMA ----------
__global__ __launch_bounds__(256) void tri_mfma_kernel(
    const __half* __restrict__ H2, const __half* __restrict__ Wt,
    __half* __restrict__ H2t, int n) {
  const int tid = threadIdx.x;
  const int m0 = blockIdx.x * 64;
  const int wave = tid >> 6;
  const int lane = tid & 63;
  const int quad = lane >> 4;
  const int l16 = lane & 15;
  const int arow = m0 + wave * 16 + l16;
  f32x4 acc[4];
#pragma unroll
  for (int i = 0; i < 4; ++i) acc[i] = (f32x4){0.f, 0.f, 0.f, 0.f};
  const f16x8* Wf = (const f16x8*)Wt;
#pragma unroll
  for (int kc = 0; kc < 2; ++kc) {
    f16x8 af = (f16x8){0, 0, 0, 0, 0, 0, 0, 0};
    if (arow < n) af = *(const f16x8*)((const _Float16*)H2 + (long long)arow * 64 + kc * 32 + quad * 8);
#pragma unroll
    for (int nb = 0; nb < 4; ++nb) {
      f16x8 bf = Wf[(kc * 4 + nb) * 64 + lane];
      acc[nb] = __builtin_amdgcn_mfma_f32_16x16x32_f16(af, bf, acc[nb], 0, 0, 0);
    }
  }
#pragma unroll
  for (int nb = 0; nb < 4; ++nb) {
    int col = nb * 16 + l16;
#pragma unroll
    for (int reg = 0; reg < 4; ++reg) {
      int rg = m0 + wave * 16 + quad * 4 + reg;
      if (rg < n) H2t[(long long)rg * 64 + col] = __float2half(acc[nb][reg]);
    }
  }
}

// ---------- mega edge-row kernel: G = prelu(satL1a + satL1b) + trib + B2 @ H2t ----------
// R6-verified config (67.5us / 3.0 TB/s): sequential head a then head b, 4x unroll each.
// (R5's head-interleave regressed: divergent tails at avg degree ~5.)
__global__ __launch_bounds__(256) void sat_l1_mega_kernel(
    const int* __restrict__ rp_a, const int* __restrict__ rp_b, const int* __restrict__ rp_B2,
    const int* __restrict__ pool,
    const float* __restrict__ ea, const __half* __restrict__ ha,
    const float* __restrict__ eb, const __half* __restrict__ hb,
    const __half* __restrict__ H2t, const float* __restrict__ trib,
    const float* __restrict__ pw, __half* __restrict__ G, int n) {
  int row = blockIdx.x * 32 + (threadIdx.x >> 3);
  if (row >= n) return;
  int l8 = threadIdx.x & 7;
  const _Float16* haf = (const _Float16*)ha;
  const _Float16* hbf = (const _Float16*)hb;
  const _Float16* h2f = (const _Float16*)H2t;
  float r[8];
  // head a, 4x unrolled
  {
    float za = 0.f, aa[8];
#pragma unroll
    for (int j = 0; j < 8; ++j) aa[j] = 0.f;
    int p0 = rp_a[row], p1 = rp_a[row + 1];
    int p = p0;
    for (; p + 4 <= p1; p += 4) {
      int c0 = pool[p + 0], c1 = pool[p + 1], c2 = pool[p + 2], c3 = pool[p + 3];
      float w0 = ea[c0], w1 = ea[c1], w2 = ea[c2], w3 = ea[c3];
      f16x8 v0 = *(const f16x8*)(haf + ((long long)c0 << 6) + (l8 << 3));
      f16x8 v1 = *(const f16x8*)(haf + ((long long)c1 << 6) + (l8 << 3));
      f16x8 v2 = *(const f16x8*)(haf + ((long long)c2 << 6) + (l8 << 3));
      f16x8 v3 = *(const f16x8*)(haf + ((long long)c3 << 6) + (l8 << 3));
      za += (w0 + w1) + (w2 + w3);
#pragma unroll
      for (int j = 0; j < 8; ++j)
        aa[j] += w0 * (float)v0[j] + w1 * (float)v1[j] + w2 * (float)v2[j] + w3 * (float)v3[j];
    }
    for (; p < p1; ++p) {
      int c = pool[p];
      float w = ea[c];
      f16x8 v = *(const f16x8*)(haf + ((long long)c << 6) + (l8 << 3));
      za += w;
#pragma unroll
      for (int j = 0; j < 8; ++j) aa[j] += w * (float)v[j];
    }
    float iz = za > 0.f ? 1.f / za : 0.f;
#pragma unroll
    for (int j = 0; j < 8; ++j) r[j] = aa[j] * iz;
  }
  // head b, 4x unrolled
  {
    float zb = 0.f, ab[8];
#pragma unroll
    for (int j = 0; j < 8; ++j) ab[j] = 0.f;
    int p0 = rp_b[row], p1 = rp_b[row + 1];
    int p = p0;
    for (; p + 4 <= p1; p += 4) {
      int c0 = pool[p + 0], c1 = pool[p + 1], c2 = pool[p + 2], c3 = pool[p + 3];
      float w0 = eb[c0], w1 = eb[c1], w2 = eb[c2], w3 = eb[c3];
      f16x8 v0 = *(const f16x8*)(hbf + ((long long)c0 << 6) + (l8 << 3));
      f16x8 v1 = *(const f16x8*)(hbf + ((long long)c1 << 6) + (l8 << 3));
      f16x8 v2 = *(const f16x8*)(hbf + ((long long)c2 << 6) + (l8 << 3));
      f16x8 v3 = *(const f16x8*)(hbf + ((long long)c3 << 6) + (l8 << 3));
      zb += (w0 + w1) + (w2 + w3);
#pragma unroll
      for (int j = 0; j < 8; ++j)
        ab[j] += w0 * (float)v0[j] + w1 * (float)v1[j] + w2 * (float)v2[j] + w3 * (float)v3[j];
    }
    for (; p < p1; ++p) {
      int c = pool[p];
      float w = eb[c];
      f16x8 v = *(const f16x8*)(hbf + ((long long)c << 6) + (l8 << 3));
      zb += w;
#pragma unroll
      for (int j = 0; j < 8; ++j) ab[j] += w * (float)v[j];
    }
    float iz = zb > 0.f ? 1.f / zb : 0.f;
#pragma unroll
    for (int j = 0; j < 8; ++j) r[j] += ab[j] * iz;
  }
  float pv = pw[0];
#pragma unroll
  for (int j = 0; j < 8; ++j) r[j] = r[j] >= 0.f ? r[j] : pv * r[j];   // H1 = prelu(...)
  // Tm = B2 @ H2t + trib (avg 1.5 entries/row; 2x unroll)
  float tm[8];
  {
    f32x4 t0 = *(const f32x4*)(trib + (l8 << 3));
    f32x4 t1 = *(const f32x4*)(trib + (l8 << 3) + 4);
#pragma unroll
    for (int j = 0; j < 4; ++j) { tm[j] = t0[j]; tm[j + 4] = t1[j]; }
  }
  {
    int p0 = rp_B2[row], p1 = rp_B2[row + 1];
    int p = p0;
    for (; p + 2 <= p1; p += 2) {
      int e0 = pool[p], e1 = pool[p + 1];
      int c0 = e0 / 3, c1 = e1 / 3;
      float s0 = (e0 - 3 * c0 == 1) ? -1.f : 1.f;
      float s1 = (e1 - 3 * c1 == 1) ? -1.f : 1.f;
      f16x8 v0 = *(const f16x8*)(h2f + ((long long)c0 << 6) + (l8 << 3));
      f16x8 v1 = *(const f16x8*)(h2f + ((long long)c1 << 6) + (l8 << 3));
#pragma unroll
      for (int j = 0; j < 8; ++j) tm[j] += s0 * (float)v0[j] + s1 * (float)v1[j];
    }
    for (; p < p1; ++p) {
      int e = pool[p];
      int c = e / 3;
      float s = (e - 3 * c == 1) ? -1.f : 1.f;
      f16x8 v = *(const f16x8*)(h2f + ((long long)c << 6) + (l8 << 3));
#pragma unroll
      for (int j = 0; j < 8; ++j) tm[j] += s * (float)v[j];
    }
  }
  f16x8 o;
#pragma unroll
  for (int j = 0; j < 8; ++j) o[j] = (_Float16)(r[j] + tm[j]);
  *(f16x8*)((_Float16*)G + (long long)row * 64 + (l8 << 3)) = o;
}

// ---------- fused: out = (prelu(satL0) + B1 @ G) / 3 ----------
// R7: sat_dual_z<float> folded into final_kernel -- eliminates the H0 buffer
// (12.8MB fp32; 25.6MB write+read traffic) and one launch.  Two sequential
// gather phases per row: L0 SAT-dual (e0/h0/e1/h1) then B1@G (8x unroll).
__global__ __launch_bounds__(256) void final_fused_kernel(
    const int* __restrict__ rp0, const int* __restrict__ rpB1,
    const int* __restrict__ pool,
    const float* __restrict__ ea, const __half* __restrict__ ha,
    const float* __restrict__ eb, const __half* __restrict__ hb,
    const float* __restrict__ pw, const __half* __restrict__ G,
    float* __restrict__ out, int n) {
  int row = blockIdx.x * 32 + (threadIdx.x >> 3);
  if (row >= n) return;
  int l8 = threadIdx.x & 7;
  const _Float16* haf = (const _Float16*)ha;
  const _Float16* hbf = (const _Float16*)hb;
  const _Float16* gf = (const _Float16*)G;
  // phase 1: SAT dual over L0 row (4x-unrolled dual-table gather)
  float za = 0.f, zb = 0.f;
  float aa[8], ab[8];
#pragma unroll
  for (int j = 0; j < 8; ++j) { aa[j] = 0.f; ab[j] = 0.f; }
  {
    int p0 = rp0[row], p1 = rp0[row + 1];
    int p = p0;
    for (; p + 4 <= p1; p += 4) {
      int c0 = pool[p], c1 = pool[p + 1], c2 = pool[p + 2], c3 = pool[p + 3];
      float wa0 = ea[c0], wa1 = ea[c1], wa2 = ea[c2], wa3 = ea[c3];
      float wb0 = eb[c0], wb1 = eb[c1], wb2 = eb[c2], wb3 = eb[c3];
      f16x8 va0 = *(const f16x8*)(haf + ((long long)c0 << 6) + (l8 << 3));
      f16x8 va1 = *(const f16x8*)(haf + ((long long)c1 << 6) + (l8 << 3));
      f16x8 va2 = *(const f16x8*)(haf + ((long long)c2 << 6) + (l8 << 3));
      f16x8 va3 = *(const f16x8*)(haf + ((long long)c3 << 6) + (l8 << 3));
      f16x8 vb0 = *(const f16x8*)(hbf + ((long long)c0 << 6) + (l8 << 3));
      f16x8 vb1 = *(const f16x8*)(hbf + ((long long)c1 << 6) + (l8 << 3));
      f16x8 vb2 = *(const f16x8*)(hbf + ((long long)c2 << 6) + (l8 << 3));
      f16x8 vb3 = *(const f16x8*)(hbf + ((long long)c3 << 6) + (l8 << 3));
      za += (wa0 + wa1) + (wa2 + wa3);
      zb += (wb0 + wb1) + (wb2 + wb3);
#pragma unroll
      for (int j = 0; j < 8; ++j) {
        aa[j] += wa0 * (float)va0[j] + wa1 * (float)va1[j] + wa2 * (float)va2[j] + wa3 * (float)va3[j];
        ab[j] += wb0 * (float)vb0[j] + wb1 * (float)vb1[j] + wb2 * (float)vb2[j] + wb3 * (float)vb3[j];
      }
    }
    for (; p < p1; ++p) {
      int c = pool[p];
      float wa = ea[c], wb = eb[c];
      f16x8 va = *(const f16x8*)(haf + ((long long)c << 6) + (l8 << 3));
      f16x8 vb = *(const f16x8*)(hbf + ((long long)c << 6) + (l8 << 3));
      za += wa;
      zb += wb;
#pragma unroll
      for (int j = 0; j < 8; ++j) {
        aa[j] += wa * (float)va[j];
        ab[j] += wb * (float)vb[j];
      }
    }
  }
  float ia = za > 0.f ? 1.f / za : 0.f;
  float ib = zb > 0.f ? 1.f / zb : 0.f;
  float pv = pw[0];
  float acc[8];
#pragma unroll
  for (int j = 0; j < 8; ++j) {
    float t = aa[j] * ia + ab[j] * ib;
    acc[j] = t >= 0.f ? t : pv * t;   // H0 = prelu(satdual)
  }
  // phase 2: B1 @ G (8x unrolled)
  {
    int p0 = rpB1[row], p1 = rpB1[row + 1];
    int p = p0;
    for (; p + 8 <= p1; p += 8) {
      int e[8];
#pragma unroll
      for (int k = 0; k < 8; ++k) e[k] = pool[p + k];
      f16x8 v[8];
#pragma unroll
      for (int k = 0; k < 8; ++k)
        v[k] = *(const f16x8*)(gf + ((long long)(e[k] >> 1) << 6) + (l8 << 3));
#pragma unroll
      for (int k = 0; k < 8; ++k) {
        float s = (e[k] & 1) ? -1.f : 1.f;
#pragma unroll
        for (int j = 0; j < 8; ++j) acc[j] += s * (float)v[k][j];
      }
    }
    for (; p + 4 <= p1; p += 4) {
      int e0 = pool[p], e1 = pool[p + 1], e2 = pool[p + 2], e3 = pool[p + 3];
      float s0 = (e0 & 1) ? -1.f : 1.f;
      float s1 = (e1 & 1) ? -1.f : 1.f;
      float s2 = (e2 & 1) ? -1.f : 1.f;
      float s3 = (e3 & 1) ? -1.f : 1.f;
      f16x8 v0 = *(const f16x8*)(gf + ((long long)(e0 >> 1) << 6) + (l8 << 3));
      f16x8 v1 = *(const f16x8*)(gf + ((long long)(e1 >> 1) << 6) + (l8 << 3));
      f16x8 v2 = *(const f16x8*)(gf + ((long long)(e2 >> 1) << 6) + (l8 << 3));
      f16x8 v3 = *(const f16x8*)(gf + ((long long)(e3 >> 1) << 6) + (l8 << 3));
#pragma unroll
      for (int j = 0; j < 8; ++j)
        acc[j] += s0 * (float)v0[j] + s1 * (float)v1[j] + s2 * (float)v2[j] + s3 * (float)v3[j];
    }
    for (; p < p1; ++p) {
      int e = pool[p];
      float s = (e & 1) ? -1.f : 1.f;
      f16x8 v = *(const f16x8*)(gf + ((long long)(e >> 1) << 6) + (l8 << 3));
#pragma unroll
      for (int j = 0; j < 8; ++j) acc[j] += s * (float)v[j];
    }
  }
  float* op = out + (long long)row * 64 + (l8 << 3);
  f32x4 o0 = {acc[0] * (1.0f / 3.0f), acc[1] * (1.0f / 3.0f), acc[2] * (1.0f / 3.0f), acc[3] * (1.0f / 3.0f)};
  f32x4 o1 = {acc[4] * (1.0f / 3.0f), acc[5] * (1.0f / 3.0f), acc[6] * (1.0f / 3.0f), acc[7] * (1.0f / 3.0f)};
  *(f32x4*)op = o0;
  *(f32x4*)(op + 4) = o1;
}

extern "C" void kernel_launch(void* const* d_in, const int* in_sizes, int n_in,
                              void* d_out, int out_size, void* d_ws, size_t ws_size,
                              hipStream_t stream) {
  const float* X0 = (const float*)d_in[0];
  const int* E1 = (const int*)d_in[1];
  const int* T2 = (const int*)d_in[2];
  const int* L0i = (const int*)d_in[3];
  const int* L1ai = (const int*)d_in[4];
  const int* L1bi = (const int*)d_in[5];
  const int* L2i = (const int*)d_in[6];
  const int* B1i = (const int*)d_in[7];
  const int* B2i = (const int*)d_in[9];
  const float* W = (const float*)d_in[11];
  const float* bvec = (const float*)d_in[12];
  // a1_w/a1_b are mathematically dead: s1[r] cancels in the row softmax.
  const float* a2w = (const float*)d_in[15];
  const float* a2b = (const float*)d_in[16];
  const float* pw = (const float*)d_in[17];
  const float* triW = (const float*)d_in[18];
  const float* trib = (const float*)d_in[19];
  float* out = (float*)d_out;

  char* base = (char*)d_ws;
  size_t off = 0;
  auto alloc = [&](size_t bytes) -> void* {
    void* p = base + off;
    off += (bytes + 255) & ~(size_t)255;
    return p;
  };
  unsigned int* Xbit = (unsigned int*)alloc((size_t)N0 * 16 * 4);
  unsigned short* Bp = (unsigned short*)alloc((size_t)3 * 65536 * 2);
  __half* Wt = (__half*)alloc((size_t)4096 * 2);
  __half* h0 = (__half*)alloc((size_t)N0 * 64 * 2);
  __half* h1 = (__half*)alloc((size_t)N0 * 64 * 2);
  __half* h2 = (__half*)alloc((size_t)N1 * 64 * 2);
  __half* h3 = (__half*)alloc((size_t)N1 * 64 * 2);
  __half* h4 = (__half*)alloc((size_t)N2 * 64 * 2);
  __half* h5 = (__half*)alloc((size_t)N2 * 64 * 2);
  float* e0 = (float*)alloc((size_t)N0 * 4);
  float* e1 = (float*)alloc((size_t)N0 * 4);
  float* e2 = (float*)alloc((size_t)N1 * 4);
  float* e3 = (float*)alloc((size_t)N1 * 4);
  float* e4 = (float*)alloc((size_t)N2 * 4);
  float* e5 = (float*)alloc((size_t)N2 * 4);
  __half* H2 = (__half*)alloc((size_t)N2 * 64 * 2);
  __half* H2t = (__half*)alloc((size_t)N2 * 64 * 2);
  __half* G = (__half*)alloc((size_t)N1 * 64 * 2);
  int* gscan = (int*)alloc((size_t)(CNT_TOT + 1) * 4);
  int* pool = (int*)alloc((size_t)TOT_E * 4);
  int* stage = (int*)alloc((size_t)TOT_E * 4);
  int* bh = (int*)alloc((size_t)BH_N * 4);
  int* bhoff = (int*)alloc((size_t)(BH_N + 1) * 4);
  int* bsum = (int*)alloc((size_t)(BH_SCAN_BLOCKS + 1) * 4);

  pack_bits_kernel<<<(N0 + 3) / 4, 256, 0, stream>>>(X0, Xbit);
  pack_w_kernel<<<(3 * 65536 + 255) / 256, 256, 0, stream>>>(W, Bp);
  pack_wt_kernel<<<16, 256, 0, stream>>>(triW, Wt);

  gemm_sat_kernel<1><<<(N0 + 127) / 128, 256, 0, stream>>>(Xbit, nullptr, Bp, bvec, a2w, a2b, 0, N0, h0, h1, e0, e1);
  gemm_sat_kernel<2><<<(N1 + 127) / 128, 256, 0, stream>>>(Xbit, E1, Bp + 65536, bvec, a2w, a2b, 2, N1, h2, h3, e2, e3);
  gemm_sat_kernel<3><<<(N2 + 127) / 128, 256, 0, stream>>>(Xbit, T2, Bp + 2 * 65536, bvec, a2w, a2b, 4, N2, h4, h5, e4, e5);

  // radix-partition CSR build (no row-level global histogram needed)
  blkhist_kernel<<<NBLK, 256, 0, stream>>>(L0i, L1ai, L1bi, L2i, B1i, B2i, bh);
  scan_partial_kernel<<<BH_SCAN_BLOCKS, 256, 0, stream>>>(bh, bsum, BH_N);
  scan_bsum_kernel<<<1, 256, 0, stream>>>(bsum, BH_SCAN_BLOCKS);
  scan_write_kernel<<<BH_SCAN_BLOCKS, 256, 0, stream>>>(bh, bsum, bhoff, BH_N, BH_SCAN_BLOCKS);
  stage_part_kernel<<<NBLK, 256, 0, stream>>>(L0i, L1ai, L1bi, L2i, B1i, B2i, bhoff, stage);
  fill_cb_kernel<<<CB, 256, 0, stream>>>(bhoff, stage, gscan, pool);

  const int* rp0 = gscan + SEG_L0;
  const int* rp1a = gscan + SEG_L1A;
  const int* rp1b = gscan + SEG_L1B;
  const int* rp2 = gscan + SEG_L2;
  const int* rpB1 = gscan + SEG_B1;
  const int* rpB2 = gscan + SEG_B2;

  sat_dual_z_kernel<<<(N2 + 31) / 32, 256, 0, stream>>>(rp2, pool, e4, h4, e5, h5, pw, H2, N2);
  tri_mfma_kernel<<<(N2 + 63) / 64, 256, 0, stream>>>(H2, Wt, H2t, N2);
  sat_l1_mega_kernel<<<(N1 + 31) / 32, 256, 0, stream>>>(rp1a, rp1b, rpB2, pool, e2, h2, e3, h3,
                                                         H2t, trib, pw, G, N1);
  final_fused_kernel<<<(N0 + 31) / 32, 256, 0, stream>>>(rp0, rpB1, pool, e0, h0, e1, h1, pw, G,
                                                         out, N0);
}

// Round 8
// 525.559 us; speedup vs baseline: 1.1030x; 1.0478x over previous
//
#include <hip/hip_runtime.h>
#include <hip/hip_fp16.h>

static constexpr int N0 = 50000;
static constexpr int N1 = 200000;
static constexpr int N2 = 100000;
static constexpr int NNZ0 = 600000;
static constexpr int NNZ1 = 1000000;
static constexpr int NNZ2 = 600000;
static constexpr int FIN = 500;

// concatenated count layout: [L0 | L1a | L1b | L2 | B1 | B2]
static constexpr int SEG_L0 = 0;
static constexpr int SEG_L1A = 50000;
static constexpr int SEG_L1B = 250000;
static constexpr int SEG_L2 = 450000;
static constexpr int SEG_B1 = 550000;
static constexpr int SEG_B2 = 600000;
static constexpr int CNT_TOT = 800000;
static constexpr int TOT_E = NNZ0 + NNZ1 + NNZ1 + NNZ2 + 2 * N1 + 3 * N2;  // 3.9M
// radix partition: 512 partition blocks x 1563 coarse buckets (512 rows each).
static constexpr int NBLK = 512;
static constexpr int EPB = (TOT_E + NBLK - 1) / NBLK;        // 7618 entries/block
static constexpr int CB_SHIFT = 9;                           // 512 rows per coarse bucket
static constexpr int CB = (CNT_TOT + (1 << CB_SHIFT) - 1) >> CB_SHIFT;  // 1563
static constexpr int BH_N = CB * NBLK;                       // 800256
static constexpr int SCAN_CHUNK = 4096;
static constexpr int BH_SCAN_BLOCKS = (BH_N + SCAN_CHUNK - 1) / SCAN_CHUNK;  // 196 (<=256 cap)

// mega-kernel block-range dispatch (R8): overlap latency-bound partition passes
// with LDS/MFMA-bound gemms on the same launch -- single stream serializes
// kernels, so independent stages otherwise waste whole-GPU time.
static constexpr int G_GEMM1 = (N0 + 127) / 128;   // 391
static constexpr int G_GEMM2 = (N1 + 127) / 128;   // 1563
static constexpr int G_GEMM3 = (N2 + 127) / 128;   // 782
static constexpr int PB_B = (N0 + 3) / 4;          // 12500
static constexpr int PW_B = 768;
static constexpr int PWT_B = 16;
static constexpr int SMEM_BYTES = 128 * 20 * 4 + 3 * 4096 * 2;  // 34816 (gemm's need)

typedef __attribute__((ext_vector_type(8))) short bf16x8;
typedef __attribute__((ext_vector_type(8))) _Float16 f16x8;
typedef __attribute__((ext_vector_type(4))) float f32x4;

typedef const unsigned int __attribute__((address_space(1)))* gas_u32p;
typedef unsigned int __attribute__((address_space(3)))* las_u32p;

__device__ __forceinline__ unsigned short f2bf(float f) {
  unsigned int b = __float_as_uint(f);
  b = (b + 0x7FFFu + ((b >> 16) & 1u)) >> 16;   // RNE
  return (unsigned short)b;
}

// ---------- pack bodies ----------
__device__ __forceinline__ void pack_bits_body(int blk, const float* __restrict__ X0,
                                               unsigned int* __restrict__ Xbit) {
  int row = blk * 4 + (threadIdx.x >> 6);
  if (row >= N0) return;
  int lane = threadIdx.x & 63;
  const float* xr = X0 + (long long)row * FIN;
#pragma unroll
  for (int i = 0; i < 8; ++i) {
    int c = i * 64 + lane;
    bool pred = (c < FIN) && (xr[c] != 0.0f);
    unsigned long long m = __ballot(pred);
    if (lane == 0) {
      Xbit[row * 16 + 2 * i] = (unsigned int)m;
      Xbit[row * 16 + 2 * i + 1] = (unsigned int)(m >> 32);
    }
  }
}

__device__ __forceinline__ void pack_w_body(int blk, const float* __restrict__ W,
                                            unsigned short* __restrict__ Bp) {
  int g = blk * 256 + threadIdx.x;
  if (g >= 3 * 65536) return;
  int j = g & 7;
  int lane = (g >> 3) & 63;
  int nb = (g >> 9) & 7;
  int kc = (g >> 12) & 15;
  int level = g >> 16;
  int k = kc * 32 + (lane >> 4) * 8 + j;
  int col128 = nb * 16 + (lane & 15);
  int head = level * 2 + (col128 >> 6);
  int col = col128 & 63;
  float f = 0.0f;
  if (k < FIN) f = W[((long long)head * FIN + k) * 64 + col];
  Bp[g] = f2bf(f);
}

__device__ __forceinline__ void pack_wt_body(int blk, const float* __restrict__ triW,
                                             __half* __restrict__ Wt) {
  int g = blk * 256 + threadIdx.x;
  if (g >= 4096) return;
  int j = g & 7;
  int lane = (g >> 3) & 63;
  int nb = (g >> 9) & 3;
  int kc = g >> 11;
  int k = kc * 32 + (lane >> 4) * 8 + j;
  int col = nb * 16 + (lane & 15);
  Wt[g] = __float2half(triW[k * 64 + col]);
}

// ---------- all packs in one launch (independent; block-range dispatch) ----------
__global__ __launch_bounds__(256) void pack_all_kernel(
    const float* __restrict__ X0, unsigned int* __restrict__ Xbit,
    const float* __restrict__ W, unsigned short* __restrict__ Bp,
    const float* __restrict__ triW, __half* __restrict__ Wt) {
  int b = blockIdx.x;
  if (b < PB_B) pack_bits_body(b, X0, Xbit);
  else if (b < PB_B + PW_B) pack_w_body(b - PB_B, W, Bp);
  else pack_wt_body(b - PB_B - PW_B, triW, Wt);
}

// ---------- fused bit-gather(AND) + in-register bf16 expansion + MFMA (device body) ----------
// B-fragments staged via global_load_lds into rotating LDS buffers (R3); 2-deep
// counted-vmcnt prefetch (R7 -- measured ~neutral: TLP from 4 blocks/CU already
// covers stage latency; kept since harmless).
template <int NSRC>
__device__ void gemm_sat_body(
    char* smem, int bid,
    const unsigned int* __restrict__ Xbit, const int* __restrict__ srcidx,
    const unsigned short* __restrict__ Bp, const float* __restrict__ bvec,
    const float* __restrict__ a2w, const float* __restrict__ a2b, int head_lo,
    int M, __half* __restrict__ h_lo, __half* __restrict__ h_hi,
    float* __restrict__ e_lo, float* __restrict__ e_hi) {
  unsigned int* Sb = (unsigned int*)smem;                                   // 10240B
  unsigned short(*Bs)[4096] = (unsigned short(*)[4096])(smem + 128 * 20 * 4);  // 3x8KB
  const int tid = threadIdx.x;
  const int m0 = bid * 128;
  const int wave = tid >> 6;
  const int lane = tid & 63;
  {
    // 2 threads per row: thread handles uint4 chunks {2*hf, 2*hf+1} of the 64B row mask
    int rg = m0 + (tid >> 1);
    int hf = tid & 1;
    uint4 a[2];
#pragma unroll
    for (int c2 = 0; c2 < 2; ++c2) a[c2] = make_uint4(0u, 0u, 0u, 0u);
    if (rg < M) {
      if (NSRC == 1) {
        const uint4* up = (const uint4*)(Xbit + (long long)rg * 16);
#pragma unroll
        for (int c2 = 0; c2 < 2; ++c2) a[c2] = up[hf * 2 + c2];
      } else if (NSRC == 2) {
        const uint4* up = (const uint4*)(Xbit + (long long)srcidx[2 * rg + 0] * 16);
        const uint4* vp = (const uint4*)(Xbit + (long long)srcidx[2 * rg + 1] * 16);
#pragma unroll
        for (int c2 = 0; c2 < 2; ++c2) {
          uint4 u = up[hf * 2 + c2], v = vp[hf * 2 + c2];
          a[c2] = make_uint4(u.x & v.x, u.y & v.y, u.z & v.z, u.w & v.w);
        }
      } else {
        const uint4* up = (const uint4*)(Xbit + (long long)srcidx[3 * rg + 0] * 16);
        const uint4* vp = (const uint4*)(Xbit + (long long)srcidx[3 * rg + 1] * 16);
        const uint4* wp = (const uint4*)(Xbit + (long long)srcidx[3 * rg + 2] * 16);
#pragma unroll
        for (int c2 = 0; c2 < 2; ++c2) {
          uint4 u = up[hf * 2 + c2], v = vp[hf * 2 + c2], w = wp[hf * 2 + c2];
          a[c2] = make_uint4(u.x & v.x & w.x, u.y & v.y & w.y, u.z & v.z & w.z, u.w & v.w & w.w);
        }
      }
    }
#pragma unroll
    for (int c2 = 0; c2 < 2; ++c2)
      *(uint4*)(Sb + (tid >> 1) * 20 + (hf * 2 + c2) * 4) = a[c2];
  }

  auto stageB = [&](int buf, int kc2) {
    int chunk0 = wave * 2;
    const unsigned short* g0 = Bp + kc2 * 4096 + chunk0 * 512 + lane * 8;
    __builtin_amdgcn_global_load_lds((gas_u32p)(const void*)g0,
                                     (las_u32p)(void*)&Bs[buf][chunk0 * 512], 16, 0, 0);
    __builtin_amdgcn_global_load_lds((gas_u32p)(const void*)(g0 + 512),
                                     (las_u32p)(void*)&Bs[buf][chunk0 * 512 + 512], 16, 0, 0);
  };
  stageB(0, 0);
  stageB(1, 1);
  __syncthreads();   // one-time full drain: Sb writes + both prologue stages complete

  const int quad = lane >> 4;
  const int l16 = lane & 15;
  f32x4 acc[8][2];   // [nb][sub]
#pragma unroll
  for (int i = 0; i < 8; ++i)
#pragma unroll
    for (int s = 0; s < 2; ++s) acc[i][s] = (f32x4){0.f, 0.f, 0.f, 0.f};

  for (int kc = 0; kc < 16; ++kc) {
    const int cur = kc % 3;
    if (kc + 2 < 16) stageB((kc + 2) % 3, kc + 2);   // 2-deep prefetch
    bf16x8 af[2];
#pragma unroll
    for (int sub = 0; sub < 2; ++sub) {
      unsigned int bw = Sb[(wave * 32 + sub * 16 + l16) * 20 + kc];
      unsigned int byte = (bw >> (quad * 8)) & 0xFFu;
#pragma unroll
      for (int j = 0; j < 4; ++j) {
        unsigned int b2 = (byte >> (2 * j)) & 3u;
        ((unsigned int*)&af[sub])[j] = ((b2 & 1u) | ((b2 & 2u) << 15)) * 0x3F80u;
      }
    }
#pragma unroll
    for (int nb = 0; nb < 8; ++nb) {
      bf16x8 bf = *(const bf16x8*)&Bs[cur][(nb * 64 + lane) * 8];
#pragma unroll
      for (int sub = 0; sub < 2; ++sub)
        acc[nb][sub] = __builtin_amdgcn_mfma_f32_16x16x32_bf16(af[sub], bf, acc[nb][sub], 0, 0, 0);
    }
    if (kc < 15) {
      if (kc + 2 < 16) asm volatile("s_waitcnt vmcnt(2)" ::: "memory");
      else             asm volatile("s_waitcnt vmcnt(0)" ::: "memory");
      __builtin_amdgcn_sched_barrier(0);
      __builtin_amdgcn_s_barrier();
    }
  }

  float bia[8], aw[8];
#pragma unroll
  for (int nb = 0; nb < 8; ++nb) {
    int col128 = nb * 16 + l16;
    int hh = col128 >> 6, col = col128 & 63;
    bia[nb] = bvec[(head_lo + hh) * 64 + col];
    aw[nb] = a2w[(head_lo + hh) * 64 + col];
  }
  float blo = a2b[head_lo], bhi = a2b[head_lo + 1];
#pragma unroll
  for (int sub = 0; sub < 2; ++sub) {
    float plo[4] = {0.f, 0.f, 0.f, 0.f};
    float phi[4] = {0.f, 0.f, 0.f, 0.f};
#pragma unroll
    for (int nb = 0; nb < 8; ++nb) {
      int col128 = nb * 16 + l16;
      int hh = col128 >> 6, col = col128 & 63;
      __half* hdst = hh ? h_hi : h_lo;
#pragma unroll
      for (int reg = 0; reg < 4; ++reg) {
        int rg = m0 + wave * 32 + sub * 16 + quad * 4 + reg;   // C/D: row=quad*4+reg, col=l16
        float v = acc[nb][sub][reg] + bia[nb];
        if (rg < M) hdst[(long long)rg * 64 + col] = __float2half(v);
        if (hh) phi[reg] += v * aw[nb]; else plo[reg] += v * aw[nb];
      }
    }
#pragma unroll
    for (int off = 1; off < 16; off <<= 1) {
#pragma unroll
      for (int reg = 0; reg < 4; ++reg) {
        plo[reg] += __shfl_xor(plo[reg], off);
        phi[reg] += __shfl_xor(phi[reg], off);
      }
    }
    if (l16 == 0) {
#pragma unroll
      for (int reg = 0; reg < 4; ++reg) {
        int rg = m0 + wave * 32 + sub * 16 + quad * 4 + reg;
        if (rg < M) {
          e_lo[rg] = __expf(plo[reg] + blo);   // |s2| small by construction: no max needed
          e_hi[rg] = __expf(phi[reg] + bhi);
        }
      }
    }
  }
}

// ---------- entry decode shared by partition passes ----------
template <bool NEED_VAL>
__device__ __forceinline__ void decode_entry(
    int g, const int* __restrict__ r0, const int* __restrict__ r1a,
    const int* __restrict__ r1b, const int* __restrict__ r2,
    const int* __restrict__ rb1, const int* __restrict__ rb2, int& row, int& val) {
  if (g < 600000) { int l = g; row = SEG_L0 + r0[l]; if (NEED_VAL) val = r0[NNZ0 + l]; }
  else if (g < 1600000) { int l = g - 600000; row = SEG_L1A + r1a[l]; if (NEED_VAL) val = r1a[NNZ1 + l]; }
  else if (g < 2600000) { int l = g - 1600000; row = SEG_L1B + r1b[l]; if (NEED_VAL) val = r1b[NNZ1 + l]; }
  else if (g < 3200000) { int l = g - 2600000; row = SEG_L2 + r2[l]; if (NEED_VAL) val = r2[NNZ2 + l]; }
  else if (g < 3600000) { int l = g - 3200000; row = SEG_B1 + rb1[l]; val = l; }   // B1: entry id
  else { int l = g - 3600000; row = SEG_B2 + rb2[l]; val = l; }                    // B2: entry id
}

// ---------- pass 1 body: per-(block, coarse-bucket) histogram via LDS, 4x MLP ----------
__device__ void blkhist_body(
    char* smem, int blk,
    const int* __restrict__ r0, const int* __restrict__ r1a, const int* __restrict__ r1b,
    const int* __restrict__ r2, const int* __restrict__ rb1, const int* __restrict__ rb2,
    int* __restrict__ bh) {
  int* hcnt = (int*)smem;   // CB ints = 6252B, fits in the gemm smem union
  for (int i = threadIdx.x; i < CB; i += 256) hcnt[i] = 0;
  __syncthreads();
  int g0 = blk * EPB;
  int g1 = g0 + EPB; if (g1 > TOT_E) g1 = TOT_E;
  int g = g0 + threadIdx.x;
  for (; g + 768 < g1; g += 1024) {
    int ra, rb, rc, rd, v;
    decode_entry<false>(g, r0, r1a, r1b, r2, rb1, rb2, ra, v);
    decode_entry<false>(g + 256, r0, r1a, r1b, r2, rb1, rb2, rb, v);
    decode_entry<false>(g + 512, r0, r1a, r1b, r2, rb1, rb2, rc, v);
    decode_entry<false>(g + 768, r0, r1a, r1b, r2, rb1, rb2, rd, v);
    atomicAdd(&hcnt[ra >> CB_SHIFT], 1);
    atomicAdd(&hcnt[rb >> CB_SHIFT], 1);
    atomicAdd(&hcnt[rc >> CB_SHIFT], 1);
    atomicAdd(&hcnt[rd >> CB_SHIFT], 1);
  }
  for (; g < g1; g += 256) {
    int row, val;
    decode_entry<false>(g, r0, r1a, r1b, r2, rb1, rb2, row, val);
    atomicAdd(&hcnt[row >> CB_SHIFT], 1);
  }
  __syncthreads();
  for (int i = threadIdx.x; i < CB; i += 256) bh[i * NBLK + blk] = hcnt[i];
}

// ---------- pass 2 body: write packed (row_lo,val) into block-private runs, 4x MLP ----------
__device__ void stage_part_body(
    char* smem, int blk,
    const int* __restrict__ r0, const int* __restrict__ r1a, const int* __restrict__ r1b,
    const int* __restrict__ r2, const int* __restrict__ rb1, const int* __restrict__ rb2,
    const int* __restrict__ bhoff, int* __restrict__ stage) {
  int* lcur = (int*)smem;
  for (int i = threadIdx.x; i < CB; i += 256) lcur[i] = bhoff[i * NBLK + blk];
  __syncthreads();
  int g0 = blk * EPB;
  int g1 = g0 + EPB; if (g1 > TOT_E) g1 = TOT_E;
  const int rmask = (1 << CB_SHIFT) - 1;
  int g = g0 + threadIdx.x;
  for (; g + 768 < g1; g += 1024) {
    int ra, rb, rc, rd, va, vb, vc, vd;
    decode_entry<true>(g, r0, r1a, r1b, r2, rb1, rb2, ra, va);
    decode_entry<true>(g + 256, r0, r1a, r1b, r2, rb1, rb2, rb, vb);
    decode_entry<true>(g + 512, r0, r1a, r1b, r2, rb1, rb2, rc, vc);
    decode_entry<true>(g + 768, r0, r1a, r1b, r2, rb1, rb2, rd, vd);
    int pa = atomicAdd(&lcur[ra >> CB_SHIFT], 1);
    int pb = atomicAdd(&lcur[rb >> CB_SHIFT], 1);
    int pc = atomicAdd(&lcur[rc >> CB_SHIFT], 1);
    int pd = atomicAdd(&lcur[rd >> CB_SHIFT], 1);
    stage[pa] = ((ra & rmask) << 20) | va;
    stage[pb] = ((rb & rmask) << 20) | vb;
    stage[pc] = ((rc & rmask) << 20) | vc;
    stage[pd] = ((rd & rmask) << 20) | vd;
  }
  for (; g < g1; g += 256) {
    int row, val;
    decode_entry<true>(g, r0, r1a, r1b, r2, rb1, rb2, row, val);
    int pos = atomicAdd(&lcur[row >> CB_SHIFT], 1);
    stage[pos] = ((row & rmask) << 20) | val;
  }
}

// ---------- MEGA_A: gemm<2> (1563 blocks) || blkhist (512 blocks) ----------
__global__ __launch_bounds__(256, 4) void mega_a_kernel(
    const unsigned int* __restrict__ Xbit, const int* __restrict__ E1,
    const unsigned short* __restrict__ Bp, const float* __restrict__ bvec,
    const float* __restrict__ a2w, const float* __restrict__ a2b,
    __half* __restrict__ h2, __half* __restrict__ h3,
    float* __restrict__ e2, float* __restrict__ e3,
    const int* __restrict__ r0, const int* __restrict__ r1a, const int* __restrict__ r1b,
    const int* __restrict__ r2, const int* __restrict__ rb1, const int* __restrict__ rb2,
    int* __restrict__ bh) {
  __shared__ __align__(16) char smem[SMEM_BYTES];
  int b = blockIdx.x;
  if (b < G_GEMM2)
    gemm_sat_body<2>(smem, b, Xbit, E1, Bp + 65536, bvec, a2w, a2b, 2, N1, h2, h3, e2, e3);
  else
    blkhist_body(smem, b - G_GEMM2, r0, r1a, r1b, r2, rb1, rb2, bh);
}

// ---------- MEGA_B: gemm<3> (782) || gemm<1> (391) || stage_part (512) ----------
__global__ __launch_bounds__(256, 4) void mega_b_kernel(
    const unsigned int* __restrict__ Xbit, const int* __restrict__ T2,
    const unsigned short* __restrict__ Bp, const float* __restrict__ bvec,
    const float* __restrict__ a2w, const float* __restrict__ a2b,
    __half* __restrict__ h0, __half* __restrict__ h1,
    float* __restrict__ e0, float* __restrict__ e1,
    __half* __restrict__ h4, __half* __restrict__ h5,
    float* __restrict__ e4, float* __restrict__ e5,
    const int* __restrict__ r0, const int* __restrict__ r1a, const int* __restrict__ r1b,
    const int* __restrict__ r2, const int* __restrict__ rb1, const int* __restrict__ rb2,
    const int* __restrict__ bhoff, int* __restrict__ stage) {
  __shared__ __align__(16) char smem[SMEM_BYTES];
  int b = blockIdx.x;
  if (b < G_GEMM3)
    gemm_sat_body<3>(smem, b, Xbit, T2, Bp + 2 * 65536, bvec, a2w, a2b, 4, N2, h4, h5, e4, e5);
  else if (b < G_GEMM3 + G_GEMM1)
    gemm_sat_body<1>(smem, b - G_GEMM3, Xbit, nullptr, Bp, bvec, a2w, a2b, 0, N0, h0, h1, e0, e1);
  else
    stage_part_body(smem, b - G_GEMM3 - G_GEMM1, r0, r1a, r1b, r2, rb1, rb2, bhoff, stage);
}

// ---------- scans (scan_bsum folded into scan_write: 196 partials scanned per-block) ----------
__global__ __launch_bounds__(256) void scan_partial_kernel(const int* __restrict__ cnt,
                                                           int* __restrict__ bsum, int n) {
  __shared__ int s[256];
  int b = blockIdx.x, t = threadIdx.x;
  int base = b * SCAN_CHUNK + t * 16;
  int sum = 0;
#pragma unroll
  for (int i = 0; i < 16; ++i) {
    int idx = base + i;
    if (idx < n) sum += cnt[idx];
  }
  s[t] = sum;
  __syncthreads();
  for (int off = 128; off > 0; off >>= 1) {
    if (t < off) s[t] += s[t + off];
    __syncthreads();
  }
  if (t == 0) bsum[b] = s[0];
}

__global__ __launch_bounds__(256) void scan_write_kernel(const int* __restrict__ cnt,
                                                         const int* __restrict__ bsum,
                                                         int* __restrict__ gout, int n, int nb) {
  __shared__ int s[256];
  int b = blockIdx.x, t = threadIdx.x;
  // phase 0: every block redundantly scans the raw per-block partials (nb<=256)
  int v = (t < nb) ? bsum[t] : 0;
  s[t] = v;
  __syncthreads();
  for (int off = 1; off < 256; off <<= 1) {
    int u = (t >= off) ? s[t - off] : 0;
    __syncthreads();
    s[t] += u;
    __syncthreads();
  }
  int boff = (b == 0) ? 0 : s[b - 1];
  int total = s[nb - 1];
  __syncthreads();
  // phase 1: local chunk scan + write
  int base = b * SCAN_CHUNK + t * 16;
  int loc[16];
  int sum = 0;
#pragma unroll
  for (int i = 0; i < 16; ++i) {
    int idx = base + i;
    int vv = (idx < n) ? cnt[idx] : 0;
    loc[i] = sum;
    sum += vv;
  }
  s[t] = sum;
  __syncthreads();
  for (int off = 1; off < 256; off <<= 1) {
    int u = (t >= off) ? s[t - off] : 0;
    __syncthreads();
    s[t] += u;
    __syncthreads();
  }
  int toff = boff + ((t == 0) ? 0 : s[t - 1]);
#pragma unroll
  for (int i = 0; i < 16; ++i) {
    int idx = base + i;
    if (idx < n) gout[idx] = toff + loc[i];
  }
  if (b == 0 && t == 0) gout[n] = total;
}

// ---------- pass 3: per coarse-bucket: derive gscan locally + scatter pool slice ----------
__global__ __launch_bounds__(256) void fill_cb_kernel(
    const int* __restrict__ bhoff, const int* __restrict__ stage,
    int* __restrict__ gscan, int* __restrict__ pool) {
  __shared__ int hist[1 << CB_SHIFT];   // 512 row counters -> offsets -> cursors
  __shared__ int sums[256];
  const int cb = blockIdx.x;
  const int t = threadIdx.x;
  const int base_row = cb << CB_SHIFT;
  int nrows = CNT_TOT - base_row;
  if (nrows > (1 << CB_SHIFT)) nrows = 1 << CB_SHIFT;
  const int s0 = bhoff[cb * NBLK];
  const int s1 = bhoff[(cb + 1) * NBLK];   // bhoff[BH_N] = TOT_E covers cb == CB-1
  for (int i = t; i < (1 << CB_SHIFT); i += 256) hist[i] = 0;
  __syncthreads();
  {
    int i = s0 + t;
    for (; i + 768 < s1; i += 1024) {
      int ra = stage[i] >> 20, rb = stage[i + 256] >> 20,
          rc = stage[i + 512] >> 20, rd = stage[i + 768] >> 20;
      atomicAdd(&hist[ra], 1);
      atomicAdd(&hist[rb], 1);
      atomicAdd(&hist[rc], 1);
      atomicAdd(&hist[rd], 1);
    }
    for (; i < s1; i += 256) atomicAdd(&hist[stage[i] >> 20], 1);
  }
  __syncthreads();
  int loc[2];
  int sum = 0;
#pragma unroll
  for (int j = 0; j < 2; ++j) { loc[j] = sum; sum += hist[t * 2 + j]; }
  sums[t] = sum;
  __syncthreads();
  for (int off = 1; off < 256; off <<= 1) {
    int u = (t >= off) ? sums[t - off] : 0;
    __syncthreads();
    sums[t] += u;
    __syncthreads();
  }
  int pre = (t == 0) ? 0 : sums[t - 1];
#pragma unroll
  for (int j = 0; j < 2; ++j) hist[t * 2 + j] = s0 + pre + loc[j];   // row start offsets
  __syncthreads();
  for (int i = t; i < nrows; i += 256) gscan[base_row + i] = hist[i];
  if (cb == CB - 1 && t == 0) gscan[CNT_TOT] = TOT_E;
  __syncthreads();
  {
    int i = s0 + t;
    for (; i + 768 < s1; i += 1024) {
      int a = stage[i], b = stage[i + 256], c = stage[i + 512], d = stage[i + 768];
      int pa = atomicAdd(&hist[a >> 20], 1);
      int pb = atomicAdd(&hist[b >> 20], 1);
      int pc = atomicAdd(&hist[c >> 20], 1);
      int pd = atomicAdd(&hist[d >> 20], 1);
      pool[pa] = a & 0xFFFFF;
      pool[pb] = b & 0xFFFFF;
      pool[pc] = c & 0xFFFFF;
      pool[pd] = d & 0xFFFFF;
    }
    for (; i < s1; i += 256) {
      int rv = stage[i];
      int pos = atomicAdd(&hist[rv >> 20], 1);
      pool[pos] = rv & 0xFFFFF;
    }
  }
}

// ---------- SAT dual (L2): 8 lanes per row, 4x-unrolled dual-table gather ----------
__global__ __launch_bounds__(256) void sat_dual_z_kernel(
    const int* __restrict__ rowptr, const int* __restrict__ col,
    const float* __restrict__ ea, const __half* __restrict__ ha,
    const float* __restrict__ eb, const __half* __restrict__ hb,
    const float* __restrict__ pw, __half* __restrict__ out, int n) {
  int row = blockIdx.x * 32 + (threadIdx.x >> 3);
  if (row >= n) return;
  int l8 = threadIdx.x & 7;
  const _Float16* haf = (const _Float16*)ha;
  const _Float16* hbf = (const _Float16*)hb;
  int p0 = rowptr[row], p1 = rowptr[row + 1];
  float za = 0.f, zb = 0.f;
  float aa[8], ab[8];
#pragma unroll
  for (int j = 0; j < 8; ++j) { aa[j] = 0.f; ab[j] = 0.f; }
  int p = p0;
  for (; p + 4 <= p1; p += 4) {
    int c0 = col[p], c1 = col[p + 1], c2 = col[p + 2], c3 = col[p + 3];
    float wa0 = ea[c0], wa1 = ea[c1], wa2 = ea[c2], wa3 = ea[c3];
    float wb0 = eb[c0], wb1 = eb[c1], wb2 = eb[c2], wb3 = eb[c3];
    f16x8 va0 = *(const f16x8*)(haf + ((long long)c0 << 6) + (l8 << 3));
    f16x8 va1 = *(const f16x8*)(haf + ((long long)c1 << 6) + (l8 << 3));
    f16x8 va2 = *(const f16x8*)(haf + ((long long)c2 << 6) + (l8 << 3));
    f16x8 va3 = *(const f16x8*)(haf + ((long long)c3 << 6) + (l8 << 3));
    f16x8 vb0 = *(const f16x8*)(hbf + ((long long)c0 << 6) + (l8 << 3));
    f16x8 vb1 = *(const f16x8*)(hbf + ((long long)c1 << 6) + (l8 << 3));
    f16x8 vb2 = *(const f16x8*)(hbf + ((long long)c2 << 6) + (l8 << 3));
    f16x8 vb3 = *(const f16x8*)(hbf + ((long long)c3 << 6) + (l8 << 3));
    za += (wa0 + wa1) + (wa2 + wa3);
    zb += (wb0 + wb1) + (wb2 + wb3);
#pragma unroll
    for (int j = 0; j < 8; ++j) {
      aa[j] += wa0 * (float)va0[j] + wa1 * (float)va1[j] + wa2 * (float)va2[j] + wa3 * (float)va3[j];
      ab[j] += wb0 * (float)vb0[j] + wb1 * (float)vb1[j] + wb2 * (float)vb2[j] + wb3 * (float)vb3[j];
    }
  }
  for (; p < p1; ++p) {
    int c = col[p];
    float wa = ea[c], wb = eb[c];
    f16x8 va = *(const f16x8*)(haf + ((long long)c << 6) + (l8 << 3));
    f16x8 vb = *(const f16x8*)(hbf + ((long long)c << 6) + (l8 << 3));
    za += wa;
    zb += wb;
#pragma unroll
    for (int j = 0; j < 8; ++j) {
      aa[j] += wa * (float)va[j];
      ab[j] += wb * (float)vb[j];
    }
  }
  float ia = za > 0.f ? 1.f / za : 0.f;
  float ib = zb > 0.f ? 1.f / zb : 0.f;
  float pv = pw[0];
  f16x8 o;
#pragma unroll
  for (int j = 0; j < 8; ++j) {
    float t = aa[j] * ia + ab[j] * ib;
    t = t >= 0.f ? t : pv * t;   // prelu
    o[j] = (_Float16)t;
  }
  *(f16x8*)((_Float16*)out + (long long)row * 64 + (l8 << 3)) = o;
}

// ---------- H2t = H2 @ triW via f16 MFMA ----------
__global__ __launch_bounds__(256) void tri_mfma_kernel(
    const __half* __restrict__ H2, const __half* __restrict__ Wt,
    __half* __restrict__ H2t, int n) {
  const int tid = threadIdx.x;
  const int m0 = blockIdx.x * 64;
  const int wave = tid >> 6;
  const int lane = tid & 63;
  const int quad = lane >> 4;
  const int l16 = lane & 15;
  const int arow = m0 + wave * 16 + l16;
  f32x4 acc[4];
#pragma unroll
  for (int i = 0; i < 4; ++i) acc[i] = (f32x4){0.f, 0.f, 0.f, 0.f};
  const f16x8* Wf = (const f16x8*)Wt;
#pragma unroll
  for (int kc = 0; kc < 2; ++kc) {
    f16x8 af = (f16x8){0, 0, 0, 0, 0, 0, 0, 0};
    if (arow < n) af = *(const f16x8*)((const _Float16*)H2 + (long long)arow * 64 + kc * 32 + quad * 8);
#pragma unroll
    for (int nb = 0; nb < 4; ++nb) {
      f16x8 bf = Wf[(kc * 4 + nb) * 64 + lane];
      acc[nb] = __builtin_amdgcn_mfma_f32_16x16x32_f16(af, bf, acc[nb], 0, 0, 0);
    }
  }
#pragma unroll
  for (int nb = 0; nb < 4; ++nb) {
    int col = nb * 16 + l16;
#pragma unroll
    for (int reg = 0; reg < 4; ++reg) {
      int rg = m0 + wave * 16 + quad * 4 + reg;
      if (rg < n) H2t[(long long)rg * 64 + col] = __float2half(acc[nb][reg]);
    }
  }
}

// ---------- mega edge-row kernel: G = prelu(satL1a + satL1b) + trib + B2 @ H2t ----------
// R6-verified config (67.5us / 3.0 TB/s): sequential head a then head b, 4x unroll each.
__global__ __launch_bounds__(256) void sat_l1_mega_kernel(
    const int* __restrict__ rp_a, const int* __restrict__ rp_b, const int* __restrict__ rp_B2,
    const int* __restrict__ pool,
    const float* __restrict__ ea, const __half* __restrict__ ha,
    const float* __restrict__ eb, const __half* __restrict__ hb,
    const __half* __restrict__ H2t, const float* __restrict__ trib,
    const float* __restrict__ pw, __half* __restrict__ G, int n) {
  int row = blockIdx.x * 32 + (threadIdx.x >> 3);
  if (row >= n) return;
  int l8 = threadIdx.x & 7;
  const _Float16* haf = (const _Float16*)ha;
  const _Float16* hbf = (const _Float16*)hb;
  const _Float16* h2f = (const _Float16*)H2t;
  float r[8];
  // head a, 4x unrolled
  {
    float za = 0.f, aa[8];
#pragma unroll
    for (int j = 0; j < 8; ++j) aa[j] = 0.f;
    int p0 = rp_a[row], p1 = rp_a[row + 1];
    int p = p0;
    for (; p + 4 <= p1; p += 4) {
      int c0 = pool[p + 0], c1 = pool[p + 1], c2 = pool[p + 2], c3 = pool[p + 3];
      float w0 = ea[c0], w1 = ea[c1], w2 = ea[c2], w3 = ea[c3];
      f16x8 v0 = *(const f16x8*)(haf + ((long long)c0 << 6) + (l8 << 3));
      f16x8 v1 = *(const f16x8*)(haf + ((long long)c1 << 6) + (l8 << 3));
      f16x8 v2 = *(const f16x8*)(haf + ((long long)c2 << 6) + (l8 << 3));
      f16x8 v3 = *(const f16x8*)(haf + ((long long)c3 << 6) + (l8 << 3));
      za += (w0 + w1) + (w2 + w3);
#pragma unroll
      for (int j = 0; j < 8; ++j)
        aa[j] += w0 * (float)v0[j] + w1 * (float)v1[j] + w2 * (float)v2[j] + w3 * (float)v3[j];
    }
    for (; p < p1; ++p) {
      int c = pool[p];
      float w = ea[c];
      f16x8 v = *(const f16x8*)(haf + ((long long)c << 6) + (l8 << 3));
      za += w;
#pragma unroll
      for (int j = 0; j < 8; ++j) aa[j] += w * (float)v[j];
    }
    float iz = za > 0.f ? 1.f / za : 0.f;
#pragma unroll
    for (int j = 0; j < 8; ++j) r[j] = aa[j] * iz;
  }
  // head b, 4x unrolled
  {
    float zb = 0.f, ab[8];
#pragma unroll
    for (int j = 0; j < 8; ++j) ab[j] = 0.f;
    int p0 = rp_b[row], p1 = rp_b[row + 1];
    int p = p0;
    for (; p + 4 <= p1; p += 4) {
      int c0 = pool[p + 0], c1 = pool[p + 1], c2 = pool[p + 2], c3 = pool[p + 3];
      float w0 = eb[c0], w1 = eb[c1], w2 = eb[c2], w3 = eb[c3];
      f16x8 v0 = *(const f16x8*)(hbf + ((long long)c0 << 6) + (l8 << 3));
      f16x8 v1 = *(const f16x8*)(hbf + ((long long)c1 << 6) + (l8 << 3));
      f16x8 v2 = *(const f16x8*)(hbf + ((long long)c2 << 6) + (l8 << 3));
      f16x8 v3 = *(const f16x8*)(hbf + ((long long)c3 << 6) + (l8 << 3));
      zb += (w0 + w1) + (w2 + w3);
#pragma unroll
      for (int j = 0; j < 8; ++j)
        ab[j] += w0 * (float)v0[j] + w1 * (float)v1[j] + w2 * (float)v2[j] + w3 * (float)v3[j];
    }
    for (; p < p1; ++p) {
      int c = pool[p];
      float w = eb[c];
      f16x8 v = *(const f16x8*)(hbf + ((long long)c << 6) + (l8 << 3));
      zb += w;
#pragma unroll
      for (int j = 0; j < 8; ++j) ab[j] += w * (float)v[j];
    }
    float iz = zb > 0.f ? 1.f / zb : 0.f;
#pragma unroll
    for (int j = 0; j < 8; ++j) r[j] += ab[j] * iz;
  }
  float pv = pw[0];
#pragma unroll
  for (int j = 0; j < 8; ++j) r[j] = r[j] >= 0.f ? r[j] : pv * r[j];   // H1 = prelu(...)
  // Tm = B2 @ H2t + trib (avg 1.5 entries/row; 2x unroll)
  float tm[8];
  {
    f32x4 t0 = *(const f32x4*)(trib + (l8 << 3));
    f32x4 t1 = *(const f32x4*)(trib + (l8 << 3) + 4);
#pragma unroll
    for (int j = 0; j < 4; ++j) { tm[j] = t0[j]; tm[j + 4] = t1[j]; }
  }
  {
    int p0 = rp_B2[row], p1 = rp_B2[row + 1];
    int p = p0;
    for (; p + 2 <= p1; p += 2) {
      int e0 = pool[p], e1 = pool[p + 1];
      int c0 = e0 / 3, c1 = e1 / 3;
      float s0 = (e0 - 3 * c0 == 1) ? -1.f : 1.f;
      float s1 = (e1 - 3 * c1 == 1) ? -1.f : 1.f;
      f16x8 v0 = *(const f16x8*)(h2f + ((long long)c0 << 6) + (l8 << 3));
      f16x8 v1 = *(const f16x8*)(h2f + ((long long)c1 << 6) + (l8 << 3));
#pragma unroll
      for (int j = 0; j < 8; ++j) tm[j] += s0 * (float)v0[j] + s1 * (float)v1[j];
    }
    for (; p < p1; ++p) {
      int e = pool[p];
      int c = e / 3;
      float s = (e - 3 * c == 1) ? -1.f : 1.f;
      f16x8 v = *(const f16x8*)(h2f + ((long long)c << 6) + (l8 << 3));
#pragma unroll
      for (int j = 0; j < 8; ++j) tm[j] += s * (float)v[j];
    }
  }
  f16x8 o;
#pragma unroll
  for (int j = 0; j < 8; ++j) o[j] = (_Float16)(r[j] + tm[j]);
  *(f16x8*)((_Float16*)G + (long long)row * 64 + (l8 << 3)) = o;
}

// ---------- fused: out = (prelu(satL0) + B1 @ G) / 3 ----------
__global__ __launch_bounds__(256) void final_fused_kernel(
    const int* __restrict__ rp0, const int* __restrict__ rpB1,
    const int* __restrict__ pool,
    const float* __restrict__ ea, const __half* __restrict__ ha,
    const float* __restrict__ eb, const __half* __restrict__ hb,
    const float* __restrict__ pw, const __half* __restrict__ G,
    float* __restrict__ out, int n) {
  int row = blockIdx.x * 32 + (threadIdx.x >> 3);
  if (row >= n) return;
  int l8 = threadIdx.x & 7;
  const _Float16* haf = (const _Float16*)ha;
  const _Float16* hbf = (const _Float16*)hb;
  const _Float16* gf = (const _Float16*)G;
  float za = 0.f, zb = 0.f;
  float aa[8], ab[8];
#pragma unroll
  for (int j = 0; j < 8; ++j) { aa[j] = 0.f; ab[j] = 0.f; }
  {
    int p0 = rp0[row], p1 = rp0[row + 1];
    int p = p0;
    for (; p + 4 <= p1; p += 4) {
      int c0 = pool[p], c1 = pool[p + 1], c2 = pool[p + 2], c3 = pool[p + 3];
      float wa0 = ea[c0], wa1 = ea[c1], wa2 = ea[c2], wa3 = ea[c3];
      float wb0 = eb[c0], wb1 = eb[c1], wb2 = eb[c2], wb3 = eb[c3];
      f16x8 va0 = *(const f16x8*)(haf + ((long long)c0 << 6) + (l8 << 3));
      f16x8 va1 = *(const f16x8*)(haf + ((long long)c1 << 6) + (l8 << 3));
      f16x8 va2 = *(const f16x8*)(haf + ((long long)c2 << 6) + (l8 << 3));
      f16x8 va3 = *(const f16x8*)(haf + ((long long)c3 << 6) + (l8 << 3));
      f16x8 vb0 = *(const f16x8*)(hbf + ((long long)c0 << 6) + (l8 << 3));
      f16x8 vb1 = *(const f16x8*)(hbf + ((long long)c1 << 6) + (l8 << 3));
      f16x8 vb2 = *(const f16x8*)(hbf + ((long long)c2 << 6) + (l8 << 3));
      f16x8 vb3 = *(const f16x8*)(hbf + ((long long)c3 << 6) + (l8 << 3));
      za += (wa0 + wa1) + (wa2 + wa3);
      zb += (wb0 + wb1) + (wb2 + wb3);
#pragma unroll
      for (int j = 0; j < 8; ++j) {
        aa[j] += wa0 * (float)va0[j] + wa1 * (float)va1[j] + wa2 * (float)va2[j] + wa3 * (float)va3[j];
        ab[j] += wb0 * (float)vb0[j] + wb1 * (float)vb1[j] + wb2 * (float)vb2[j] + wb3 * (float)vb3[j];
      }
    }
    for (; p < p1; ++p) {
      int c = pool[p];
      float wa = ea[c], wb = eb[c];
      f16x8 va = *(const f16x8*)(haf + ((long long)c << 6) + (l8 << 3));
      f16x8 vb = *(const f16x8*)(hbf + ((long long)c << 6) + (l8 << 3));
      za += wa;
      zb += wb;
#pragma unroll
      for (int j = 0; j < 8; ++j) {
        aa[j] += wa * (float)va[j];
        ab[j] += wb * (float)vb[j];
      }
    }
  }
  float ia = za > 0.f ? 1.f / za : 0.f;
  float ib = zb > 0.f ? 1.f / zb : 0.f;
  float pv = pw[0];
  float acc[8];
#pragma unroll
  for (int j = 0; j < 8; ++j) {
    float t = aa[j] * ia + ab[j] * ib;
    acc[j] = t >= 0.f ? t : pv * t;   // H0 = prelu(satdual)
  }
  {
    int p0 = rpB1[row], p1 = rpB1[row + 1];
    int p = p0;
    for (; p + 8 <= p1; p += 8) {
      int e[8];
#pragma unroll
      for (int k = 0; k < 8; ++k) e[k] = pool[p + k];
      f16x8 v[8];
#pragma unroll
      for (int k = 0; k < 8; ++k)
        v[k] = *(const f16x8*)(gf + ((long long)(e[k] >> 1) << 6) + (l8 << 3));
#pragma unroll
      for (int k = 0; k < 8; ++k) {
        float s = (e[k] & 1) ? -1.f : 1.f;
#pragma unroll
        for (int j = 0; j < 8; ++j) acc[j] += s * (float)v[k][j];
      }
    }
    for (; p + 4 <= p1; p += 4) {
      int e0 = pool[p], e1 = pool[p + 1], e2 = pool[p + 2], e3 = pool[p + 3];
      float s0 = (e0 & 1) ? -1.f : 1.f;
      float s1 = (e1 & 1) ? -1.f : 1.f;
      float s2 = (e2 & 1) ? -1.f : 1.f;
      float s3 = (e3 & 1) ? -1.f : 1.f;
      f16x8 v0 = *(const f16x8*)(gf + ((long long)(e0 >> 1) << 6) + (l8 << 3));
      f16x8 v1 = *(const f16x8*)(gf + ((long long)(e1 >> 1) << 6) + (l8 << 3));
      f16x8 v2 = *(const f16x8*)(gf + ((long long)(e2 >> 1) << 6) + (l8 << 3));
      f16x8 v3 = *(const f16x8*)(gf + ((long long)(e3 >> 1) << 6) + (l8 << 3));
#pragma unroll
      for (int j = 0; j < 8; ++j)
        acc[j] += s0 * (float)v0[j] + s1 * (float)v1[j] + s2 * (float)v2[j] + s3 * (float)v3[j];
    }
    for (; p < p1; ++p) {
      int e = pool[p];
      float s = (e & 1) ? -1.f : 1.f;
      f16x8 v = *(const f16x8*)(gf + ((long long)(e >> 1) << 6) + (l8 << 3));
#pragma unroll
      for (int j = 0; j < 8; ++j) acc[j] += s * (float)v[j];
    }
  }
  float* op = out + (long long)row * 64 + (l8 << 3);
  f32x4 o0 = {acc[0] * (1.0f / 3.0f), acc[1] * (1.0f / 3.0f), acc[2] * (1.0f / 3.0f), acc[3] * (1.0f / 3.0f)};
  f32x4 o1 = {acc[4] * (1.0f / 3.0f), acc[5] * (1.0f / 3.0f), acc[6] * (1.0f / 3.0f), acc[7] * (1.0f / 3.0f)};
  *(f32x4*)op = o0;
  *(f32x4*)(op + 4) = o1;
}

extern "C" void kernel_launch(void* const* d_in, const int* in_sizes, int n_in,
                              void* d_out, int out_size, void* d_ws, size_t ws_size,
                              hipStream_t stream) {
  const float* X0 = (const float*)d_in[0];
  const int* E1 = (const int*)d_in[1];
  const int* T2 = (const int*)d_in[2];
  const int* L0i = (const int*)d_in[3];
  const int* L1ai = (const int*)d_in[4];
  const int* L1bi = (const int*)d_in[5];
  const int* L2i = (const int*)d_in[6];
  const int* B1i = (const int*)d_in[7];
  const int* B2i = (const int*)d_in[9];
  const float* W = (const float*)d_in[11];
  const float* bvec = (const float*)d_in[12];
  // a1_w/a1_b are mathematically dead: s1[r] cancels in the row softmax.
  const float* a2w = (const float*)d_in[15];
  const float* a2b = (const float*)d_in[16];
  const float* pw = (const float*)d_in[17];
  const float* triW = (const float*)d_in[18];
  const float* trib = (const float*)d_in[19];
  float* out = (float*)d_out;

  char* base = (char*)d_ws;
  size_t off = 0;
  auto alloc = [&](size_t bytes) -> void* {
    void* p = base + off;
    off += (bytes + 255) & ~(size_t)255;
    return p;
  };
  unsigned int* Xbit = (unsigned int*)alloc((size_t)N0 * 16 * 4);
  unsigned short* Bp = (unsigned short*)alloc((size_t)3 * 65536 * 2);
  __half* Wt = (__half*)alloc((size_t)4096 * 2);
  __half* h0 = (__half*)alloc((size_t)N0 * 64 * 2);
  __half* h1 = (__half*)alloc((size_t)N0 * 64 * 2);
  __half* h2 = (__half*)alloc((size_t)N1 * 64 * 2);
  __half* h3 = (__half*)alloc((size_t)N1 * 64 * 2);
  __half* h4 = (__half*)alloc((size_t)N2 * 64 * 2);
  __half* h5 = (__half*)alloc((size_t)N2 * 64 * 2);
  float* e0 = (float*)alloc((size_t)N0 * 4);
  float* e1 = (float*)alloc((size_t)N0 * 4);
  float* e2 = (float*)alloc((size_t)N1 * 4);
  float* e3 = (float*)alloc((size_t)N1 * 4);
  float* e4 = (float*)alloc((size_t)N2 * 4);
  float* e5 = (float*)alloc((size_t)N2 * 4);
  __half* H2 = (__half*)alloc((size_t)N2 * 64 * 2);
  __half* H2t = (__half*)alloc((size_t)N2 * 64 * 2);
  __half* G = (__half*)alloc((size_t)N1 * 64 * 2);
  int* gscan = (int*)alloc((size_t)(CNT_TOT + 1) * 4);
  int* pool = (int*)alloc((size_t)TOT_E * 4);
  int* stage = (int*)alloc((size_t)TOT_E * 4);
  int* bh = (int*)alloc((size_t)BH_N * 4);
  int* bhoff = (int*)alloc((size_t)(BH_N + 1) * 4);
  int* bsum = (int*)alloc((size_t)(BH_SCAN_BLOCKS + 1) * 4);

  // 1: all packs (independent)
  pack_all_kernel<<<PB_B + PW_B + PWT_B, 256, 0, stream>>>(X0, Xbit, W, Bp, triW, Wt);

  // 2: gemm<2> || blkhist (independent; overlap latency-bound pass under MFMA pass)
  mega_a_kernel<<<G_GEMM2 + NBLK, 256, 0, stream>>>(Xbit, E1, Bp, bvec, a2w, a2b,
                                                    h2, h3, e2, e3,
                                                    L0i, L1ai, L1bi, L2i, B1i, B2i, bh);

  // 3-4: scans (scan_bsum folded into scan_write)
  scan_partial_kernel<<<BH_SCAN_BLOCKS, 256, 0, stream>>>(bh, bsum, BH_N);
  scan_write_kernel<<<BH_SCAN_BLOCKS, 256, 0, stream>>>(bh, bsum, bhoff, BH_N, BH_SCAN_BLOCKS);

  // 5: gemm<3> || gemm<1> || stage_part
  mega_b_kernel<<<G_GEMM3 + G_GEMM1 + NBLK, 256, 0, stream>>>(
      Xbit, T2, Bp, bvec, a2w, a2b, h0, h1, e0, e1, h4, h5, e4, e5,
      L0i, L1ai, L1bi, L2i, B1i, B2i, bhoff, stage);

  // 6: finish CSR build
  fill_cb_kernel<<<CB, 256, 0, stream>>>(bhoff, stage, gscan, pool);

  const int* rp0 = gscan + SEG_L0;
  const int* rp1a = gscan + SEG_L1A;
  const int* rp1b = gscan + SEG_L1B;
  const int* rp2 = gscan + SEG_L2;
  const int* rpB1 = gscan + SEG_B1;
  const int* rpB2 = gscan + SEG_B2;

  sat_dual_z_kernel<<<(N2 + 31) / 32, 256, 0, stream>>>(rp2, pool, e4, h4, e5, h5, pw, H2, N2);
  tri_mfma_kernel<<<(N2 + 63) / 64, 256, 0, stream>>>(H2, Wt, H2t, N2);
  sat_l1_mega_kernel<<<(N1 + 31) / 32, 256, 0, stream>>>(rp1a, rp1b, rpB2, pool, e2, h2, e3, h3,
                                                         H2t, trib, pw, G, N1);
  final_fused_kernel<<<(N0 + 31) / 32, 256, 0, stream>>>(rp0, rpB1, pool, e0, h0, e1, h1, pw, G,
                                                         out, N0);
}